// Round 9
// baseline (388.551 us; speedup 1.0000x reference)
//
#include <hip/hip_runtime.h>
#include <hip/hip_bf16.h>

// Problem constants: B=2, L=2048, D=2048, H=16, Dh=128, 3D=6144
typedef unsigned short ushort_t;
typedef __attribute__((ext_vector_type(4))) float fvec4;
typedef __attribute__((ext_vector_type(16))) float fvec16;
typedef __attribute__((ext_vector_type(8))) short short8;   // 8 bf16 (4 VGPRs) - MFMA A/B frag
typedef __attribute__((ext_vector_type(4))) unsigned short usvec4;
typedef __attribute__((ext_vector_type(2))) unsigned int uvec2;

typedef const __attribute__((address_space(1))) void* gas_ptr;
typedef __attribute__((address_space(3))) void* las_ptr;

__device__ __forceinline__ void glds16(const void* g, void* l) {
  // async global->LDS, 16B/lane, LDS dest = wave-uniform base + lane*16
  __builtin_amdgcn_global_load_lds((gas_ptr)g, (las_ptr)l, 16, 0, 0);
}

__device__ __forceinline__ ushort_t f2bf(float f) {
  unsigned u = __float_as_uint(f);
  u += 0x7FFFu + ((u >> 16) & 1u);   // RNE
  return (ushort_t)(u >> 16);
}
__device__ __forceinline__ float bf2f(ushort_t h) {
  return __uint_as_float(((unsigned)h) << 16);
}

// permlane32_swap: a' = [a.lo32lanes, b.lo32lanes], b' = [a.hi, b.hi]
__device__ __forceinline__ void swap32(unsigned& a, unsigned& b) {
#if __has_builtin(__builtin_amdgcn_permlane32_swap)
  uvec2 r = __builtin_amdgcn_permlane32_swap(a, b, false, false);
  a = r[0]; b = r[1];
#else
  const unsigned sa = (unsigned)__shfl_xor((int)a, 32);
  const unsigned sb = (unsigned)__shfl_xor((int)b, 32);
  const bool hi = (threadIdx.x & 32) != 0;
  const unsigned na = hi ? sb : a;
  const unsigned nb = hi ? b : sa;
  a = na; b = nb;
#endif
}

// ---------------------------------------------------------------- cast x -> bf16
__global__ __launch_bounds__(256) void cast_f32_bf16(const float* __restrict__ X,
                                                     ushort_t* __restrict__ Xb) {
  const size_t i = ((size_t)blockIdx.x * 256 + threadIdx.x) * 4;
  const fvec4 v = *(const fvec4*)(X + i);
  usvec4 o;
  o[0] = f2bf(v[0]); o[1] = f2bf(v[1]); o[2] = f2bf(v[2]); o[3] = f2bf(v[3]);
  *(usvec4*)(Xb + i) = o;
}

// ------------------------------------- transpose+cast weights: W(Kd,Nd) -> Wt(Nd,Kd) bf16
__global__ __launch_bounds__(256) void tcast(const float* __restrict__ W,
                                             ushort_t* __restrict__ Wt,
                                             const int Kd, const int Nd) {
  __shared__ float ls[64][65];
  const int t = threadIdx.x;
  const int n0 = blockIdx.x * 64, k0 = blockIdx.y * 64;
  const int kr = t >> 4, nc = (t & 15) * 4;
#pragma unroll
  for (int it = 0; it < 4; ++it) {
    const fvec4 v = *(const fvec4*)(W + (size_t)(k0 + it * 16 + kr) * Nd + n0 + nc);
    ls[it * 16 + kr][nc + 0] = v[0];
    ls[it * 16 + kr][nc + 1] = v[1];
    ls[it * 16 + kr][nc + 2] = v[2];
    ls[it * 16 + kr][nc + 3] = v[3];
  }
  __syncthreads();
  const int nr = t >> 2, kg = (t & 3) * 16;
  __align__(16) ushort_t tmp[16];
#pragma unroll
  for (int i = 0; i < 16; ++i) tmp[i] = f2bf(ls[kg + i][nr]);
  ushort_t* dst = Wt + (size_t)(n0 + nr) * Kd + k0 + kg;
  *(short8*)(dst)     = *(const short8*)(tmp);
  *(short8*)(dst + 8) = *(const short8*)(tmp + 8);
}

#define FENCE asm volatile("" ::: "memory")

// ---------------- shared GEMM helpers (T2 swizzle: pre-swizzled global k-chunk;
// reads XOR (row&7)<<4 into the 16B-slot bits; LDS row = 64 ushorts = 128 B)
__device__ __forceinline__ void stage_one(const ushort_t* __restrict__ G, const int grow,
                                          const int K, const int tk, ushort_t* ldsmat,
                                          const int lrow0, const int wv, const int lane) {
  const int rr = lane >> 3;                     // row within 8-row group (= row&7 of global)
  const int kk = ((lane & 7) ^ rr) * 8;         // pre-swizzled global k-chunk (ushorts)
  glds16(G + (size_t)(grow + wv * 8 + rr) * K + tk + kk,
         ldsmat + (lrow0 + wv * 8) * 64);
}

// A-frag read with {0,1,2,3}->{0,2,1,3} 64-row block permute (gemm192 A only)
__device__ __forceinline__ short8 frag_ld(const ushort_t* ldsmat, const int rbase,
                                          const int kc, const int quad, const int mm) {
  const int r = rbase + mm;                     // global row within tile
  const int blk = r >> 6;
  const int pblk = ((blk & 1) << 1) | (blk >> 1);   // {0,1,2,3}->{0,2,1,3}
  const int ldsrow = pblk * 64 + (r & 63);
  const int kb = (kc * 64 + quad * 16) ^ ((mm & 7) << 4);   // swizzled byte-in-row
  return *(const short8*)(ldsmat + ldsrow * 64 + (kb >> 1));
}

// identity-layout frag read (gemm128 A/B, gemm192 B)
__device__ __forceinline__ short8 fragld128(const ushort_t* mat, const int row,
                                            const int kc, const int quad) {
  const int kb = (kc * 64 + quad * 16) ^ ((row & 7) << 4);
  return *(const short8*)(mat + row * 64 + (kb >> 1));
}

// ================================================================ 256x192 8-phase GEMM
// REGISTER-PREFETCH version (benched r8: 101 µs QKV).  BM=256, BN=192, BK=64,
// 512 thr = 8 waves (2M x 4N), per-wave 128x48 (acc[8][3]).  LDS 112 KiB.
// Grid QKV = 16x32 = 512 blocks = 2 exact rounds at 1 block/CU.
// Full schedule/ledger documentation: see round-8 version (unchanged here).
#define G192_RD_A(dst_, Am, q_)                                               \
  dst_[0][0] = frag_ld(Am, wr * 128 + (q_) * 32,      0, quad, mm);           \
  dst_[0][1] = frag_ld(Am, wr * 128 + (q_) * 32,      1, quad, mm);           \
  dst_[1][0] = frag_ld(Am, wr * 128 + (q_) * 32 + 16, 0, quad, mm);           \
  dst_[1][1] = frag_ld(Am, wr * 128 + (q_) * 32 + 16, 1, quad, mm);

#define G192_RD_B(dst_, Bm)                                                   \
  _Pragma("unroll")                                                           \
  for (int j = 0; j < 3; ++j) {                                               \
    dst_[j][0] = fragld128(Bm, wc * 48 + j * 16 + mm, 0, quad);               \
    dst_[j][1] = fragld128(Bm, wc * 48 + j * 16 + mm, 1, quad);               \
  }

#define G192_MFMA(af_, bf_, q_)                                               \
  __builtin_amdgcn_s_setprio(1);                                              \
  _Pragma("unroll")                                                           \
  for (int ii = 0; ii < 2; ++ii)                                              \
  _Pragma("unroll")                                                           \
  for (int j = 0; j < 3; ++j) {                                               \
    acc[(q_) * 2 + ii][j] = __builtin_amdgcn_mfma_f32_16x16x32_bf16(          \
        af_[ii][0], bf_[j][0], acc[(q_) * 2 + ii][j], 0, 0, 0);               \
    acc[(q_) * 2 + ii][j] = __builtin_amdgcn_mfma_f32_16x16x32_bf16(          \
        af_[ii][1], bf_[j][1], acc[(q_) * 2 + ii][j], 0, 0, 0);               \
  }                                                                           \
  __builtin_amdgcn_s_setprio(0);                                              \
  __builtin_amdgcn_sched_barrier(0);

__global__ __launch_bounds__(512, 2) void gemm192p(
    const ushort_t* __restrict__ A, const ushort_t* __restrict__ Bt,
    const int M, const int N, const int K, const int mode,
    float* __restrict__ C,
    ushort_t* __restrict__ Qo, ushort_t* __restrict__ Ko, ushort_t* __restrict__ Vo) {
  __shared__ __align__(16) ushort_t lds[2][28672];   // per slot: A[0..16383], B[16384..28671]

  const int tid = threadIdx.x, wv = tid >> 6, lane = tid & 63;
  const int quad = lane >> 4, mm = lane & 15;
  const int wr = wv >> 2, wc = wv & 3;   // 2M x 4N

  const int nwg = gridDim.x, ntx = N / 192;
  const int bid = blockIdx.x;
  const int swz = (bid & 7) * (nwg >> 3) + (bid >> 3);
  const int by = swz / ntx, bx = swz - by * ntx;
  const int row0 = by * 256, col0 = bx * 192;

  fvec4 acc[8][3];
#pragma unroll
  for (int i = 0; i < 8; ++i)
#pragma unroll
    for (int j = 0; j < 3; ++j) acc[i][j] = (fvec4){0.f, 0.f, 0.f, 0.f};

  short8 bfrE[3][2], bfrO[3][2];
  short8 afE[2][2], afO[2][2];

  ushort_t* A0 = &lds[0][0];      ushort_t* B0 = &lds[0][16384];
  ushort_t* A1 = &lds[1][0];      ushort_t* B1 = &lds[1][16384];

  // ---- prologue: tile0 {b0,b1,b2,c0,c1,c2,c3} + tile1 {b0,b1,b2,c0,c2} = 12 glds
  stage_one(Bt, col0 + 0,   K, 0,  B0, 0,   wv, lane); FENCE;
  stage_one(Bt, col0 + 64,  K, 0,  B0, 64,  wv, lane); FENCE;
  stage_one(Bt, col0 + 128, K, 0,  B0, 128, wv, lane); FENCE;
  stage_one(A,  row0 + 0,   K, 0,  A0, 0,   wv, lane); FENCE;
  stage_one(A,  row0 + 64,  K, 0,  A0, 128, wv, lane); FENCE;   // c1 -> pblk 2
  stage_one(A,  row0 + 128, K, 0,  A0, 64,  wv, lane); FENCE;   // c2 -> pblk 1
  stage_one(A,  row0 + 192, K, 0,  A0, 192, wv, lane); FENCE;
  stage_one(Bt, col0 + 0,   K, 64, B1, 0,   wv, lane); FENCE;
  stage_one(Bt, col0 + 64,  K, 64, B1, 64,  wv, lane); FENCE;
  stage_one(Bt, col0 + 128, K, 64, B1, 128, wv, lane); FENCE;
  stage_one(A,  row0 + 0,   K, 64, A1, 0,   wv, lane); FENCE;
  stage_one(A,  row0 + 128, K, 64, A1, 64,  wv, lane); FENCE;
  asm volatile("s_waitcnt vmcnt(5)" ::: "memory");   // tile0 landed; tile1's 5 float
  __builtin_amdgcn_s_barrier();                      // all waves confirmed tile0
  // ph1's fragments, read ahead of the loop:
  G192_RD_B(bfrE, B0);
  G192_RD_A(afE, A0, 0);

  const int nit = K >> 7;                 // iterations of 2 K-tiles
  for (int i = 0; i < nit; ++i) {
    const bool more = (i + 1 < nit);
    const int kA = i * 128 + 64;          // tile 2i+1
    const int kB = i * 128 + 128;         // tile 2i+2
    const int kC = i * 128 + 192;         // tile 2i+3
    { // ph1
      __builtin_amdgcn_s_barrier();
      stage_one(A, row0 + 64,  K, kA, A1, 128, wv, lane); FENCE;
      stage_one(A, row0 + 192, K, kA, A1, 192, wv, lane);
      G192_MFMA(afE, bfrE, 0);
      G192_RD_A(afO, A0, 1);
    }
    { // ph2
      __builtin_amdgcn_s_barrier();
      if (more) { stage_one(Bt, col0 + 0,  K, kB, B0, 0,  wv, lane); FENCE;
                  stage_one(Bt, col0 + 64, K, kB, B0, 64, wv, lane); }
      G192_MFMA(afO, bfrE, 1);
      G192_RD_A(afE, A0, 2);
    }
    { // ph3: vmcnt(3) confirms tile 2i+1 (s1) before ph4's barrier
      __builtin_amdgcn_s_barrier();
      if (more) { stage_one(Bt, col0 + 128, K, kB, B0, 128, wv, lane);
                  asm volatile("s_waitcnt vmcnt(3)" ::: "memory");
      } else {    asm volatile("s_waitcnt vmcnt(0)" ::: "memory"); }
      G192_MFMA(afE, bfrE, 2);
      G192_RD_A(afO, A0, 3);
    }
    { // ph4: cross-slot ahead-read (B1 + A1-q0), safe after barrier
      __builtin_amdgcn_s_barrier();
      if (more) { stage_one(A, row0 + 0,   K, kB, A0, 0,  wv, lane); FENCE;
                  stage_one(A, row0 + 128, K, kB, A0, 64, wv, lane); }
      G192_MFMA(afO, bfrE, 3);
      G192_RD_B(bfrO, B1);
      G192_RD_A(afE, A1, 0);
    }
    { // ph5
      __builtin_amdgcn_s_barrier();
      if (more) { stage_one(A, row0 + 64,  K, kB, A0, 128, wv, lane); FENCE;
                  stage_one(A, row0 + 192, K, kB, A0, 192, wv, lane); }
      G192_MFMA(afE, bfrO, 0);
      G192_RD_A(afO, A1, 1);
    }
    { // ph6
      __builtin_amdgcn_s_barrier();
      if (more) { stage_one(Bt, col0 + 0,  K, kC, B1, 0,  wv, lane); FENCE;
                  stage_one(Bt, col0 + 64, K, kC, B1, 64, wv, lane); }
      G192_MFMA(afO, bfrO, 1);
      G192_RD_A(afE, A1, 2);
    }
    { // ph7: vmcnt(3) confirms tile 2i+2 (s0) before ph8's barrier
      __builtin_amdgcn_s_barrier();
      if (more) { stage_one(Bt, col0 + 128, K, kC, B1, 128, wv, lane);
                  asm volatile("s_waitcnt vmcnt(3)" ::: "memory"); }
      G192_MFMA(afE, bfrO, 2);
      G192_RD_A(afO, A1, 3);
    }
    { // ph8: cross-slot ahead-read (B0 + A0-q0) for next iteration
      __builtin_amdgcn_s_barrier();
      if (more) { stage_one(A, row0 + 0,   K, kC, A1, 0,  wv, lane); FENCE;
                  stage_one(A, row0 + 128, K, kC, A1, 64, wv, lane); }
      G192_MFMA(afO, bfrO, 3);
      if (more) { G192_RD_B(bfrE, B0); G192_RD_A(afE, A0, 0); }
    }
  }

  // ---- epilogue: per-wave 128 rows x 48 cols at (row0 + wr*128, col0 + wc*48)
  if (mode == 0) {
#pragma unroll
    for (int i = 0; i < 8; ++i)
#pragma unroll
      for (int r = 0; r < 4; ++r) {
        const int row = row0 + wr * 128 + i * 16 + quad * 4 + r;
        float* cr = C + (size_t)row * N + col0 + wc * 48;
#pragma unroll
        for (int j = 0; j < 3; ++j) cr[j * 16 + mm] = acc[i][j][r];
      }
  } else {
#pragma unroll
    for (int j = 0; j < 3; ++j) {
      const int gcolj = col0 + wc * 48 + j * 16;   // 16-aligned: one head per j-block
      const int which = gcolj >> 11;               // 0:q 1:k 2:v
      const int h = (gcolj >> 7) & 15;
      const int coff = (gcolj & 127) + mm;
      ushort_t* dst = (which == 0) ? Qo : (which == 1) ? Ko : Vo;
#pragma unroll
      for (int i = 0; i < 8; ++i)
#pragma unroll
        for (int r = 0; r < 4; ++r) {
          const int row = row0 + wr * 128 + i * 16 + quad * 4 + r;
          const int bb = row >> 11, l = row & 2047;
          dst[((size_t)(bb * 16 + h) * 2048 + l) * 128 + coff] = f2bf(acc[i][j][r]);
        }
    }
  }
}

// ================================================================ 128x256 4-phase GEMM
// (proj: 32x8 = 256 blocks = 1 exact round; proven round-4 kernel, unchanged)
__device__ __forceinline__ void stage_a128(const ushort_t* __restrict__ G, const int row0,
                                           const int K, const int tk, ushort_t* ldsA,
                                           const int wv, const int lane) {
  const int rr = lane >> 3;
  const int kk = ((lane & 7) ^ rr) * 8;
  const int r = wv * 8 + rr;
  glds16(G + (size_t)(row0 + r) * K + tk + kk,      ldsA + (wv * 8) * 64);
  glds16(G + (size_t)(row0 + 64 + r) * K + tk + kk, ldsA + (64 + wv * 8) * 64);
}
__device__ __forceinline__ void stage_b128(const ushort_t* __restrict__ G, const int col0,
                                           const int K, const int tk, ushort_t* ldsB,
                                           const int u, const int wv, const int lane) {
  const int rr = lane >> 3;
  const int kk = ((lane & 7) ^ rr) * 8;
  const int r = u * 64 + wv * 8 + rr;
  glds16(G + (size_t)(col0 + r) * K + tk + kk,       ldsB + (u * 64 + wv * 8) * 64);
  glds16(G + (size_t)(col0 + 128 + r) * K + tk + kk, ldsB + (128 + u * 64 + wv * 8) * 64);
}

__global__ __launch_bounds__(512, 2) void gemm128(
    const ushort_t* __restrict__ A, const ushort_t* __restrict__ Bt,
    const int M, const int N, const int K, const int mode,
    float* __restrict__ C,
    ushort_t* __restrict__ Qo, ushort_t* __restrict__ Ko, ushort_t* __restrict__ Vo) {
  __shared__ __align__(16) ushort_t l128[2][24576];   // per slot: A[0..8191], B[8192..24575]

  const int tid = threadIdx.x, wv = tid >> 6, lane = tid & 63;
  const int quad = lane >> 4, mm = lane & 15;
  const int wr = wv >> 2, wc = wv & 3;   // 2M x 4N

  const int nwg = gridDim.x, ntx = N >> 8;
  const int bid = blockIdx.x;
  const int swz = (bid & 7) * (nwg >> 3) + (bid >> 3);
  const int by = swz / ntx, bx = swz - by * ntx;
  const int row0 = by * 128, col0 = bx * 256;

  fvec4 acc[4][4];
#pragma unroll
  for (int m = 0; m < 4; ++m)
#pragma unroll
    for (int j = 0; j < 4; ++j) acc[m][j] = (fvec4){0.f, 0.f, 0.f, 0.f};

  ushort_t* A0 = &l128[0][0];     ushort_t* B0 = &l128[0][8192];
  ushort_t* A1 = &l128[1][0];     ushort_t* B1 = &l128[1][8192];

  short8 bfr[4][2];

  stage_b128(Bt, col0, K, 0,  B0, 0, wv, lane); FENCE;
  stage_b128(Bt, col0, K, 0,  B0, 1, wv, lane); FENCE;
  stage_a128(A,  row0, K, 0,  A0,    wv, lane); FENCE;
  stage_b128(Bt, col0, K, 64, B1, 0, wv, lane); FENCE;
  stage_b128(Bt, col0, K, 64, B1, 1, wv, lane); FENCE;
  asm volatile("s_waitcnt vmcnt(4)" ::: "memory");
  __builtin_amdgcn_s_barrier();

  const int nit = K >> 7;
  for (int i = 0; i < nit; ++i) {
    const bool more = (i + 1 < nit);
    const int kA = i * 128 + 64;
    const int kB = i * 128 + 128;
    const int kC = i * 128 + 192;
    { // ph1
      stage_a128(A, row0, K, kA, A1, wv, lane);
      short8 af[4];
#pragma unroll
      for (int m = 0; m < 4; ++m) af[m] = fragld128(A0, wr * 64 + m * 16 + mm, 0, quad);
#pragma unroll
      for (int j = 0; j < 4; ++j) {
        bfr[j][0] = fragld128(B0, wc * 64 + j * 16 + mm, 0, quad);
        bfr[j][1] = fragld128(B0, wc * 64 + j * 16 + mm, 1, quad);
      }
      __builtin_amdgcn_s_setprio(1);
#pragma unroll
      for (int m = 0; m < 4; ++m)
#pragma unroll
        for (int j = 0; j < 4; ++j)
          acc[m][j] = __builtin_amdgcn_mfma_f32_16x16x32_bf16(af[m], bfr[j][0], acc[m][j], 0, 0, 0);
      __builtin_amdgcn_s_setprio(0);
      asm volatile("s_waitcnt lgkmcnt(0)" ::: "memory");
      __builtin_amdgcn_sched_barrier(0);
    }
    { // ph2
      __builtin_amdgcn_s_barrier();
      if (more) { stage_b128(Bt, col0, K, kB, B0, 0, wv, lane); FENCE;
                  stage_b128(Bt, col0, K, kB, B0, 1, wv, lane); FENCE; }
      if (more) { asm volatile("s_waitcnt vmcnt(4)" ::: "memory"); }
      else      { asm volatile("s_waitcnt vmcnt(0)" ::: "memory"); }
      short8 af[4];
#pragma unroll
      for (int m = 0; m < 4; ++m) af[m] = fragld128(A0, wr * 64 + m * 16 + mm, 1, quad);
      __builtin_amdgcn_s_setprio(1);
#pragma unroll
      for (int m = 0; m < 4; ++m)
#pragma unroll
        for (int j = 0; j < 4; ++j)
          acc[m][j] = __builtin_amdgcn_mfma_f32_16x16x32_bf16(af[m], bfr[j][1], acc[m][j], 0, 0, 0);
      __builtin_amdgcn_s_setprio(0);
    }
    { // ph3
      __builtin_amdgcn_s_barrier();
      if (more) stage_a128(A, row0, K, kB, A0, wv, lane);
      short8 af[4];
#pragma unroll
      for (int m = 0; m < 4; ++m) af[m] = fragld128(A1, wr * 64 + m * 16 + mm, 0, quad);
#pragma unroll
      for (int j = 0; j < 4; ++j) {
        bfr[j][0] = fragld128(B1, wc * 64 + j * 16 + mm, 0, quad);
        bfr[j][1] = fragld128(B1, wc * 64 + j * 16 + mm, 1, quad);
      }
      __builtin_amdgcn_s_setprio(1);
#pragma unroll
      for (int m = 0; m < 4; ++m)
#pragma unroll
        for (int j = 0; j < 4; ++j)
          acc[m][j] = __builtin_amdgcn_mfma_f32_16x16x32_bf16(af[m], bfr[j][0], acc[m][j], 0, 0, 0);
      __builtin_amdgcn_s_setprio(0);
      asm volatile("s_waitcnt lgkmcnt(0)" ::: "memory");
      __builtin_amdgcn_sched_barrier(0);
    }
    { // ph4
      __builtin_amdgcn_s_barrier();
      if (more) { stage_b128(Bt, col0, K, kC, B1, 0, wv, lane); FENCE;
                  stage_b128(Bt, col0, K, kC, B1, 1, wv, lane); FENCE;
                  asm volatile("s_waitcnt vmcnt(4)" ::: "memory"); }
      short8 af[4];
#pragma unroll
      for (int m = 0; m < 4; ++m) af[m] = fragld128(A1, wr * 64 + m * 16 + mm, 1, quad);
      __builtin_amdgcn_s_setprio(1);
#pragma unroll
      for (int m = 0; m < 4; ++m)
#pragma unroll
        for (int j = 0; j < 4; ++j)
          acc[m][j] = __builtin_amdgcn_mfma_f32_16x16x32_bf16(af[m], bfr[j][1], acc[m][j], 0, 0, 0);
      __builtin_amdgcn_s_setprio(0);
      __builtin_amdgcn_s_barrier();
    }
  }

  if (mode == 0) {
#pragma unroll
    for (int m = 0; m < 4; ++m)
#pragma unroll
      for (int r = 0; r < 4; ++r) {
        const int row = row0 + wr * 64 + m * 16 + quad * 4 + r;
        float* cr = C + (size_t)row * N + col0 + wc * 64;
#pragma unroll
        for (int j = 0; j < 4; ++j) cr[j * 16 + mm] = acc[m][j][r];
      }
  } else {
    const int gcol = col0 + wc * 64;
    const int which = gcol >> 11;
    const int h = (gcol >> 7) & 15;
    const int coff = gcol & 127;
    ushort_t* dst = (which == 0) ? Qo : (which == 1) ? Ko : Vo;
#pragma unroll
    for (int m = 0; m < 4; ++m)
#pragma unroll
      for (int r = 0; r < 4; ++r) {
        const int row = row0 + wr * 64 + m * 16 + quad * 4 + r;
        const int bb = row >> 11, l = row & 2047;
        ushort_t* dr = dst + ((size_t)(bb * 16 + h) * 2048 + l) * 128 + coff;
#pragma unroll
        for (int j = 0; j < 4; ++j) dr[j * 16 + mm] = f2bf(acc[m][j][r]);
      }
  }
}

// ---------------------------------------------------------------- RoPE in-place on Q,K
// VECTORIZED (round 9): one thread rotates 8 consecutive (d, d+64) pairs via
// short8 loads/stores (32B/thread vs 4B/thread scalar — G13).  Math identical
// per element to the scalar version (same exp2f/floorf/__sincosf sequence).
__global__ __launch_bounds__(256) void rope_kernel(ushort_t* Qb, ushort_t* Kb) {
  const int gid = blockIdx.x * 256 + threadIdx.x;   // 2048*256 = 524288
  const int pd0 = (gid & 7) * 8;
  const int row = gid >> 3;      // b*H*L + h*L + l   (0..65535)
  const int l = row & 2047;
  ushort_t* base = (blockIdx.y ? Kb : Qb) + (size_t)row * 128;
  const short8 va = *(const short8*)(base + pd0);
  const short8 vb = *(const short8*)(base + pd0 + 64);
  short8 oa, ob;
  const float fl = (float)l;
  const bool isQ = (blockIdx.y == 0);
#pragma unroll
  for (int i = 0; i < 8; ++i) {
    const int pd = pd0 + i;
    const float a  = bf2f((ushort_t)va[i]);
    const float bv = bf2f((ushort_t)vb[i]);
    const float invf_rev = exp2f(-(float)pd * 0.20762050593045702f) * 0.15915494309189535f;
    float rev = fl * invf_rev;
    rev -= floorf(rev);                         // [0,1)
    const float ang = rev * 6.283185307179586f;
    float s, c;
    __sincosf(ang, &s, &c);
    float na = a * c - bv * s;
    float nb = bv * c + a * s;
    if (isQ) { na *= 0.08838834764831845f; nb *= 0.08838834764831845f; }
    oa[i] = (short)f2bf(na);
    ob[i] = (short)f2bf(nb);
  }
  *(short8*)(base + pd0)      = oa;
  *(short8*)(base + pd0 + 64) = ob;
}

// ---------------------------------------------------------------- V transpose per head
__global__ __launch_bounds__(256) void vtrans_kernel(const ushort_t* __restrict__ Vn,
                                                     ushort_t* __restrict__ Vt) {
  __shared__ ushort_t ls[128 * 132];
  const int bh = blockIdx.x >> 4;
  const int l0 = (blockIdx.x & 15) * 128;
  const int t = threadIdx.x;
  const ushort_t* src = Vn + ((size_t)bh * 2048 + l0) * 128;
#pragma unroll
  for (int it = 0; it < 16; ++it) {
    const int c = it * 256 + t;
    const int lr = c >> 5, dc = (c & 31) * 4;
    *(usvec4*)(ls + lr * 132 + dc) = *(const usvec4*)(src + lr * 128 + dc);
  }
  __syncthreads();
  ushort_t* dstb = Vt + (size_t)bh * 128 * 2048 + l0;
#pragma unroll
  for (int it = 0; it < 16; ++it) {
    const int c = it * 256 + t;
    const int d = c >> 5, lc = (c & 31) * 4;
    usvec4 o;
    o[0] = ls[(lc + 0) * 132 + d];
    o[1] = ls[(lc + 1) * 132 + d];
    o[2] = ls[(lc + 2) * 132 + d];
    o[3] = ls[(lc + 3) * 132 + d];
    *(usvec4*)(dstb + (size_t)d * 2048 + lc) = o;
  }
}

// ---------------------------------------------------------------- flash attention v2
// Round-9 change: BALANCED CU PAIRING.  Old map qi = 15-(bid>>5) pairs blocks
// (c, c+256) on one CU (round-robin dispatch) as qi sums {22,20,...,8} -> worst
// CU 48 tile-iters vs mean 34.  New map: first 256 bids get qi 0..7, second 256
// get qi 15..8, so (c, c+256) always sums to qi_a+qi_b=15 => every CU runs
// exactly 36 tile-iters (perfect balance; mapping stays bijective over (bh,qi)).
__global__ __launch_bounds__(256, 2) void flash_kernel(
    const ushort_t* __restrict__ Qb, const ushort_t* __restrict__ Kb,
    const ushort_t* __restrict__ Vt, const int* __restrict__ am,
    ushort_t* __restrict__ Y) {
  __shared__ __align__(16) ushort_t lK[2][8192];
  __shared__ __align__(16) ushort_t lV[2][8192];
  __shared__ float lds_l[128];

  const int tid = threadIdx.x, wv = tid >> 6, lane = tid & 63;
  const int lh = lane >> 5, cq = lane & 31;
  const int bid = blockIdx.x;
  const int bh = bid & 31;
  const int idx = (bid >> 5) & 7;
  const int qi = (bid >> 8) ? (15 - idx) : idx;    // balanced (c, c+256) pairing
  const int b = bh >> 4, head = bh & 15;
  const size_t qkBase = (size_t)bh * (2048 * 128);
  const int qb = qi * 128 + wv * 32;
  const int q = qb + cq;

  unsigned fullbits = 0;
  {
    const int* amr = am + b * 2048;
#pragma unroll
    for (int rgn = 0; rgn < 4; ++rgn) {
      const int4 a0 = *(const int4*)(amr + rgn * 512 + lane * 8);
      const int4 a1 = *(const int4*)(amr + rgn * 512 + lane * 8 + 4);
      const bool ok8 = a0.x && a0.y && a0.z && a0.w && a1.x && a1.y && a1.z && a1.w;
      const unsigned long long bal = __ballot(ok8);
#pragma unroll
      for (int tt = 0; tt < 8; ++tt)
        fullbits |= ((((bal >> (8 * tt)) & 0xFFull) == 0xFFull) ? 1u : 0u) << (rgn * 8 + tt);
    }
  }

  short8 qf[8];
  {
    const ushort_t* qrow = Qb + qkBase + (size_t)q * 128;
#pragma unroll
    for (int c = 0; c < 8; ++c) qf[c] = *(const short8*)(qrow + c * 16 + lh * 8);
  }

  fvec16 yacc[4];
#pragma unroll
  for (int i = 0; i < 4; ++i)
#pragma unroll
    for (int r = 0; r < 16; ++r) yacc[i][r] = 0.f;
  float psum = 0.f;

#define FLASH_STAGE(dK, dV, kk0)                                                          \
  _Pragma("unroll")                                                                       \
  for (int it = 0; it < 4; ++it) {                                                        \
    const int f_ = it * 4 + wv;                                                           \
    const int ct_ = f_ >> 3, c_ = f_ & 7;                                                 \
    glds16(Kb + qkBase + (size_t)((kk0) + ct_ * 32 + cq) * 128 + c_ * 16 + lh * 8,        \
           (dK) + f_ * 512);                                                              \
    const int dt_ = f_ >> 2, kc_ = f_ & 3;                                                \
    glds16(Vt + ((size_t)bh * 128 + dt_ * 32 + cq) * 2048 + (kk0) + kc_ * 16 + lh * 8,    \
           (dV) + f_ * 512);                                                              \
  }

  const int nt = qi * 2 + 2;
  FLASH_STAGE(&lK[0][0], &lV[0][0], 0)
  __syncthreads();

  int cur = 0;
  for (int t = 0; t < nt; ++t) {
    const int k0 = t * 64;
    if (t + 1 < nt) {
      FLASH_STAGE(&lK[cur ^ 1][0], &lV[cur ^ 1][0], k0 + 64)
    }

    if (k0 <= qb + 31) {
      const ushort_t* bK = &lK[cur][0];
      const ushort_t* bV = &lV[cur][0];
      const bool maskfull = (fullbits >> t) & 1u;
      unsigned long long keymask = ~0ull;
      if (!maskfull) keymask = __ballot(am[b * 2048 + k0 + lane] != 0);
      const bool fullvalid = (k0 + 63 <= qb) && maskfull;

#pragma unroll
      for (int ct = 0; ct < 2; ++ct) {
        fvec16 sA_, sB_;
#pragma unroll
        for (int r = 0; r < 16; ++r) { sA_[r] = 0.f; sB_[r] = 0.f; }
        __builtin_amdgcn_s_setprio(1);
#pragma unroll
        for (int c = 0; c < 4; ++c) {
          short8 kf = *(const short8*)(bK + (ct * 8 + c) * 512 + lane * 8);
          sA_ = __builtin_amdgcn_mfma_f32_32x32x16_bf16(kf, qf[c], sA_, 0, 0, 0);
        }
#pragma unroll
        for (int c = 4; c < 8; ++c) {
          short8 kf = *(const short8*)(bK + (ct * 8 + c) * 512 + lane * 8);
          sB_ = __builtin_amdgcn_mfma_f32_32x32x16_bf16(kf, qf[c], sB_, 0, 0, 0);
        }
        __builtin_amdgcn_s_setprio(0);
        float p[16];
        if (fullvalid) {
#pragma unroll
          for (int r = 0; r < 16; ++r) p[r] = __expf(sA_[r] + sB_[r]);
        } else {
#pragma unroll
          for (int r = 0; r < 16; ++r) {
            const int kl = (r & 3) + 8 * (r >> 2) + 4 * lh + ct * 32;
            const bool ok = (k0 + kl <= q) && (((keymask >> kl) & 1ull) != 0);
            p[r] = ok ? __expf(sA_[r] + sB_[r]) : 0.f;
          }
        }
#pragma unroll
        for (int r = 0; r < 16; ++r) psum += p[r];
        unsigned pk[8];
#pragma unroll
        for (int j = 0; j < 8; ++j) {
          __hip_bfloat162 t2 = __float22bfloat162_rn(make_float2(p[2 * j], p[2 * j + 1]));
          pk[j] = *(unsigned*)&t2;
        }
#pragma unroll
        for (int kc2 = 0; kc2 < 2; ++kc2) {
          unsigned a0 = pk[kc2 * 4 + 0], a2 = pk[kc2 * 4 + 2];
          unsigned a1 = pk[kc2 * 4 + 1], a3 = pk[kc2 * 4 + 3];
          swap32(a0, a2);
          swap32(a1, a3);
          union { unsigned u[4]; short8 s; } pf;
          pf.u[0] = a0; pf.u[1] = a1; pf.u[2] = a2; pf.u[3] = a3;
          const int kc = ct * 2 + kc2;
          __builtin_amdgcn_s_setprio(1);
#pragma unroll
          for (int dt = 0; dt < 4; ++dt) {
            short8 vf = *(const short8*)(bV + (dt * 4 + kc) * 512 + lane * 8);
            yacc[dt] = __builtin_amdgcn_mfma_f32_32x32x16_bf16(pf.s, vf, yacc[dt], 0, 0, 0);
          }
          __builtin_amdgcn_s_setprio(0);
        }
      }
    }
    __syncthreads();
    cur ^= 1;
  }
#undef FLASH_STAGE

  psum += __shfl_xor(psum, 32);
  if (lane < 32) lds_l[wv * 32 + lane] = psum;
  float inv16[16];
#pragma unroll
  for (int r = 0; r < 16; ++r)
    inv16[r] = 1.f / lds_l[wv * 32 + (r & 3) + 8 * (r >> 2) + 4 * lh];

#pragma unroll
  for (int dt = 0; dt < 4; ++dt)
#pragma unroll
    for (int r = 0; r < 16; ++r) {
      const int qloc = (r & 3) + 8 * (r >> 2) + 4 * lh;
      ushort_t* dst = Y + ((size_t)(b * 2048 + qb + qloc)) * 2048 + head * 128 + dt * 32 + cq;
      *dst = f2bf(yacc[dt][r] * inv16[r]);
    }
}

// ---------------------------------------------------------------- launch
extern "C" void kernel_launch(void* const* d_in, const int* in_sizes, int n_in,
                              void* d_out, int out_size, void* d_ws, size_t ws_size,
                              hipStream_t stream) {
  const float* x      = (const float*)d_in[0];
  const int*   amask  = (const int*)d_in[1];
  const float* w_qkv  = (const float*)d_in[2];
  const float* w_proj = (const float*)d_in[3];

  ushort_t* xb     = (ushort_t*)d_ws;          // 8,388,608   (dead after gemm1)
  ushort_t* wqkvT  = xb + 8388608;             // 12,582,912  (dead after gemm1)
  ushort_t* wprojT = wqkvT + 12582912;         // 4,194,304
  ushort_t* Qb     = wprojT + 4194304;         // 8,388,608
  ushort_t* Kb     = Qb + 8388608;             // 8,388,608
  ushort_t* Vn     = Kb + 8388608;             // 8,388,608  -> total 96 MiB
  ushort_t* Vt     = wqkvT;                    // reuse
  ushort_t* Yb     = xb;                       // reuse

  cast_f32_bf16<<<8192, 256, 0, stream>>>(x, xb);
  tcast<<<dim3(96, 32), 256, 0, stream>>>(w_qkv, wqkvT, 2048, 6144);
  tcast<<<dim3(32, 32), 256, 0, stream>>>(w_proj, wprojT, 2048, 2048);
  gemm192p<<<512, 512, 0, stream>>>(xb, wqkvT, 4096, 6144, 2048, 1,
                                    nullptr, Qb, Kb, Vn);
  rope_kernel<<<dim3(2048, 2), 256, 0, stream>>>(Qb, Kb);
  vtrans_kernel<<<512, 256, 0, stream>>>(Vn, Vt);
  flash_kernel<<<512, 256, 0, stream>>>(Qb, Kb, Vt, amask, Yb);
  gemm128<<<256, 512, 0, stream>>>(Yb, wprojT, 4096, 2048, 2048, 0,
                                   (float*)d_out, nullptr, nullptr, nullptr);
}

// Round 10
// 359.960 us; speedup vs baseline: 1.0794x; 1.0794x over previous
//
#include <hip/hip_runtime.h>
#include <hip/hip_bf16.h>

// Problem constants: B=2, L=2048, D=2048, H=16, Dh=128, 3D=6144
typedef unsigned short ushort_t;
typedef __attribute__((ext_vector_type(4))) float fvec4;
typedef __attribute__((ext_vector_type(16))) float fvec16;
typedef __attribute__((ext_vector_type(8))) short short8;   // 8 bf16 (4 VGPRs) - MFMA A/B frag
typedef __attribute__((ext_vector_type(4))) unsigned short usvec4;
typedef __attribute__((ext_vector_type(2))) unsigned int uvec2;

typedef const __attribute__((address_space(1))) void* gas_ptr;
typedef __attribute__((address_space(3))) void* las_ptr;

__device__ __forceinline__ void glds16(const void* g, void* l) {
  // async global->LDS, 16B/lane, LDS dest = wave-uniform base + lane*16
  __builtin_amdgcn_global_load_lds((gas_ptr)g, (las_ptr)l, 16, 0, 0);
}

__device__ __forceinline__ ushort_t f2bf(float f) {
  unsigned u = __float_as_uint(f);
  u += 0x7FFFu + ((u >> 16) & 1u);   // RNE
  return (ushort_t)(u >> 16);
}
__device__ __forceinline__ float bf2f(ushort_t h) {
  return __uint_as_float(((unsigned)h) << 16);
}

// permlane32_swap: a' = [a.lo32lanes, b.lo32lanes], b' = [a.hi, b.hi]
__device__ __forceinline__ void swap32(unsigned& a, unsigned& b) {
#if __has_builtin(__builtin_amdgcn_permlane32_swap)
  uvec2 r = __builtin_amdgcn_permlane32_swap(a, b, false, false);
  a = r[0]; b = r[1];
#else
  const unsigned sa = (unsigned)__shfl_xor((int)a, 32);
  const unsigned sb = (unsigned)__shfl_xor((int)b, 32);
  const bool hi = (threadIdx.x & 32) != 0;
  const unsigned na = hi ? sb : a;
  const unsigned nb = hi ? b : sa;
  a = na; b = nb;
#endif
}

// ---------------------------------------------------------------- cast x -> bf16
__global__ __launch_bounds__(256) void cast_f32_bf16(const float* __restrict__ X,
                                                     ushort_t* __restrict__ Xb) {
  const size_t i = ((size_t)blockIdx.x * 256 + threadIdx.x) * 4;
  const fvec4 v = *(const fvec4*)(X + i);
  usvec4 o;
  o[0] = f2bf(v[0]); o[1] = f2bf(v[1]); o[2] = f2bf(v[2]); o[3] = f2bf(v[3]);
  *(usvec4*)(Xb + i) = o;
}

// ------------- transpose+cast BOTH weights in one launch (round 10 merge):
// bx<96 -> w_qkv (Nd=6144), else w_proj (Nd=2048).  Kd=2048 for both.
__global__ __launch_bounds__(256) void tcast2(const float* __restrict__ Wq,
                                              ushort_t* __restrict__ Wqt,
                                              const float* __restrict__ Wp,
                                              ushort_t* __restrict__ Wpt) {
  __shared__ float ls[64][65];
  const int t = threadIdx.x;
  int bx = blockIdx.x;
  const float* W; ushort_t* Wt; int Nd;
  if (bx < 96) { W = Wq; Wt = Wqt; Nd = 6144; }
  else         { bx -= 96; W = Wp; Wt = Wpt; Nd = 2048; }
  const int Kd = 2048;
  const int n0 = bx * 64, k0 = blockIdx.y * 64;
  const int kr = t >> 4, nc = (t & 15) * 4;
#pragma unroll
  for (int it = 0; it < 4; ++it) {
    const fvec4 v = *(const fvec4*)(W + (size_t)(k0 + it * 16 + kr) * Nd + n0 + nc);
    ls[it * 16 + kr][nc + 0] = v[0];
    ls[it * 16 + kr][nc + 1] = v[1];
    ls[it * 16 + kr][nc + 2] = v[2];
    ls[it * 16 + kr][nc + 3] = v[3];
  }
  __syncthreads();
  const int nr = t >> 2, kg = (t & 3) * 16;
  __align__(16) ushort_t tmp[16];
#pragma unroll
  for (int i = 0; i < 16; ++i) tmp[i] = f2bf(ls[kg + i][nr]);
  ushort_t* dst = Wt + (size_t)(n0 + nr) * Kd + k0 + kg;
  *(short8*)(dst)     = *(const short8*)(tmp);
  *(short8*)(dst + 8) = *(const short8*)(tmp + 8);
}

#define FENCE asm volatile("" ::: "memory")

// ---------------- shared GEMM helpers (T2 swizzle: pre-swizzled global k-chunk;
// reads XOR (row&7)<<4 into the 16B-slot bits; LDS row = 64 ushorts = 128 B)
__device__ __forceinline__ void stage_one(const ushort_t* __restrict__ G, const int grow,
                                          const int K, const int tk, ushort_t* ldsmat,
                                          const int lrow0, const int wv, const int lane) {
  const int rr = lane >> 3;                     // row within 8-row group (= row&7 of global)
  const int kk = ((lane & 7) ^ rr) * 8;         // pre-swizzled global k-chunk (ushorts)
  glds16(G + (size_t)(grow + wv * 8 + rr) * K + tk + kk,
         ldsmat + (lrow0 + wv * 8) * 64);
}

// A-frag read with {0,1,2,3}->{0,2,1,3} 64-row block permute (gemm192 A only)
__device__ __forceinline__ short8 frag_ld(const ushort_t* ldsmat, const int rbase,
                                          const int kc, const int quad, const int mm) {
  const int r = rbase + mm;                     // global row within tile
  const int blk = r >> 6;
  const int pblk = ((blk & 1) << 1) | (blk >> 1);   // {0,1,2,3}->{0,2,1,3}
  const int ldsrow = pblk * 64 + (r & 63);
  const int kb = (kc * 64 + quad * 16) ^ ((mm & 7) << 4);   // swizzled byte-in-row
  return *(const short8*)(ldsmat + ldsrow * 64 + (kb >> 1));
}

// identity-layout frag read (gemm128 A/B, gemm192 B)
__device__ __forceinline__ short8 fragld128(const ushort_t* mat, const int row,
                                            const int kc, const int quad) {
  const int kb = (kc * 64 + quad * 16) ^ ((row & 7) << 4);
  return *(const short8*)(mat + row * 64 + (kb >> 1));
}

// ================================================================ 256x192 8-phase GEMM
// REGISTER-PREFETCH version (benched r8/r9: ~103 µs QKV).  BM=256, BN=192, BK=64,
// 512 thr = 8 waves (2M x 4N), per-wave 128x48 (acc[8][3]).  LDS 112 KiB.
// Grid QKV = 16x32 = 512 blocks = 2 exact rounds at 1 block/CU.
// Round-10 change: V output (which==2) is written DIRECTLY TRANSPOSED to the
// Vt (B,H,Dh,L) buffer — eliminates the vtrans kernel and its 50 MB round-trip.
#define G192_RD_A(dst_, Am, q_)                                               \
  dst_[0][0] = frag_ld(Am, wr * 128 + (q_) * 32,      0, quad, mm);           \
  dst_[0][1] = frag_ld(Am, wr * 128 + (q_) * 32,      1, quad, mm);           \
  dst_[1][0] = frag_ld(Am, wr * 128 + (q_) * 32 + 16, 0, quad, mm);           \
  dst_[1][1] = frag_ld(Am, wr * 128 + (q_) * 32 + 16, 1, quad, mm);

#define G192_RD_B(dst_, Bm)                                                   \
  _Pragma("unroll")                                                           \
  for (int j = 0; j < 3; ++j) {                                               \
    dst_[j][0] = fragld128(Bm, wc * 48 + j * 16 + mm, 0, quad);               \
    dst_[j][1] = fragld128(Bm, wc * 48 + j * 16 + mm, 1, quad);               \
  }

#define G192_MFMA(af_, bf_, q_)                                               \
  __builtin_amdgcn_s_setprio(1);                                              \
  _Pragma("unroll")                                                           \
  for (int ii = 0; ii < 2; ++ii)                                              \
  _Pragma("unroll")                                                           \
  for (int j = 0; j < 3; ++j) {                                               \
    acc[(q_) * 2 + ii][j] = __builtin_amdgcn_mfma_f32_16x16x32_bf16(          \
        af_[ii][0], bf_[j][0], acc[(q_) * 2 + ii][j], 0, 0, 0);               \
    acc[(q_) * 2 + ii][j] = __builtin_amdgcn_mfma_f32_16x16x32_bf16(          \
        af_[ii][1], bf_[j][1], acc[(q_) * 2 + ii][j], 0, 0, 0);               \
  }                                                                           \
  __builtin_amdgcn_s_setprio(0);                                              \
  __builtin_amdgcn_sched_barrier(0);

__global__ __launch_bounds__(512, 2) void gemm192p(
    const ushort_t* __restrict__ A, const ushort_t* __restrict__ Bt,
    const int M, const int N, const int K, const int mode,
    float* __restrict__ C,
    ushort_t* __restrict__ Qo, ushort_t* __restrict__ Ko, ushort_t* __restrict__ Vo) {
  __shared__ __align__(16) ushort_t lds[2][28672];   // per slot: A[0..16383], B[16384..28671]

  const int tid = threadIdx.x, wv = tid >> 6, lane = tid & 63;
  const int quad = lane >> 4, mm = lane & 15;
  const int wr = wv >> 2, wc = wv & 3;   // 2M x 4N

  const int nwg = gridDim.x, ntx = N / 192;
  const int bid = blockIdx.x;
  const int swz = (bid & 7) * (nwg >> 3) + (bid >> 3);
  const int by = swz / ntx, bx = swz - by * ntx;
  const int row0 = by * 256, col0 = bx * 192;

  fvec4 acc[8][3];
#pragma unroll
  for (int i = 0; i < 8; ++i)
#pragma unroll
    for (int j = 0; j < 3; ++j) acc[i][j] = (fvec4){0.f, 0.f, 0.f, 0.f};

  short8 bfrE[3][2], bfrO[3][2];
  short8 afE[2][2], afO[2][2];

  ushort_t* A0 = &lds[0][0];      ushort_t* B0 = &lds[0][16384];
  ushort_t* A1 = &lds[1][0];      ushort_t* B1 = &lds[1][16384];

  // ---- prologue: tile0 {b0,b1,b2,c0,c1,c2,c3} + tile1 {b0,b1,b2,c0,c2} = 12 glds
  stage_one(Bt, col0 + 0,   K, 0,  B0, 0,   wv, lane); FENCE;
  stage_one(Bt, col0 + 64,  K, 0,  B0, 64,  wv, lane); FENCE;
  stage_one(Bt, col0 + 128, K, 0,  B0, 128, wv, lane); FENCE;
  stage_one(A,  row0 + 0,   K, 0,  A0, 0,   wv, lane); FENCE;
  stage_one(A,  row0 + 64,  K, 0,  A0, 128, wv, lane); FENCE;   // c1 -> pblk 2
  stage_one(A,  row0 + 128, K, 0,  A0, 64,  wv, lane); FENCE;   // c2 -> pblk 1
  stage_one(A,  row0 + 192, K, 0,  A0, 192, wv, lane); FENCE;
  stage_one(Bt, col0 + 0,   K, 64, B1, 0,   wv, lane); FENCE;
  stage_one(Bt, col0 + 64,  K, 64, B1, 64,  wv, lane); FENCE;
  stage_one(Bt, col0 + 128, K, 64, B1, 128, wv, lane); FENCE;
  stage_one(A,  row0 + 0,   K, 64, A1, 0,   wv, lane); FENCE;
  stage_one(A,  row0 + 128, K, 64, A1, 64,  wv, lane); FENCE;
  asm volatile("s_waitcnt vmcnt(5)" ::: "memory");   // tile0 landed; tile1's 5 float
  __builtin_amdgcn_s_barrier();                      // all waves confirmed tile0
  // ph1's fragments, read ahead of the loop:
  G192_RD_B(bfrE, B0);
  G192_RD_A(afE, A0, 0);

  const int nit = K >> 7;                 // iterations of 2 K-tiles
  for (int i = 0; i < nit; ++i) {
    const bool more = (i + 1 < nit);
    const int kA = i * 128 + 64;          // tile 2i+1
    const int kB = i * 128 + 128;         // tile 2i+2
    const int kC = i * 128 + 192;         // tile 2i+3
    { // ph1
      __builtin_amdgcn_s_barrier();
      stage_one(A, row0 + 64,  K, kA, A1, 128, wv, lane); FENCE;
      stage_one(A, row0 + 192, K, kA, A1, 192, wv, lane);
      G192_MFMA(afE, bfrE, 0);
      G192_RD_A(afO, A0, 1);
    }
    { // ph2
      __builtin_amdgcn_s_barrier();
      if (more) { stage_one(Bt, col0 + 0,  K, kB, B0, 0,  wv, lane); FENCE;
                  stage_one(Bt, col0 + 64, K, kB, B0, 64, wv, lane); }
      G192_MFMA(afO, bfrE, 1);
      G192_RD_A(afE, A0, 2);
    }
    { // ph3: vmcnt(3) confirms tile 2i+1 (s1) before ph4's barrier
      __builtin_amdgcn_s_barrier();
      if (more) { stage_one(Bt, col0 + 128, K, kB, B0, 128, wv, lane);
                  asm volatile("s_waitcnt vmcnt(3)" ::: "memory");
      } else {    asm volatile("s_waitcnt vmcnt(0)" ::: "memory"); }
      G192_MFMA(afE, bfrE, 2);
      G192_RD_A(afO, A0, 3);
    }
    { // ph4: cross-slot ahead-read (B1 + A1-q0), safe after barrier
      __builtin_amdgcn_s_barrier();
      if (more) { stage_one(A, row0 + 0,   K, kB, A0, 0,  wv, lane); FENCE;
                  stage_one(A, row0 + 128, K, kB, A0, 64, wv, lane); }
      G192_MFMA(afO, bfrE, 3);
      G192_RD_B(bfrO, B1);
      G192_RD_A(afE, A1, 0);
    }
    { // ph5
      __builtin_amdgcn_s_barrier();
      if (more) { stage_one(A, row0 + 64,  K, kB, A0, 128, wv, lane); FENCE;
                  stage_one(A, row0 + 192, K, kB, A0, 192, wv, lane); }
      G192_MFMA(afE, bfrO, 0);
      G192_RD_A(afO, A1, 1);
    }
    { // ph6
      __builtin_amdgcn_s_barrier();
      if (more) { stage_one(Bt, col0 + 0,  K, kC, B1, 0,  wv, lane); FENCE;
                  stage_one(Bt, col0 + 64, K, kC, B1, 64, wv, lane); }
      G192_MFMA(afO, bfrO, 1);
      G192_RD_A(afE, A1, 2);
    }
    { // ph7: vmcnt(3) confirms tile 2i+2 (s0) before ph8's barrier
      __builtin_amdgcn_s_barrier();
      if (more) { stage_one(Bt, col0 + 128, K, kC, B1, 128, wv, lane);
                  asm volatile("s_waitcnt vmcnt(3)" ::: "memory"); }
      G192_MFMA(afE, bfrO, 2);
      G192_RD_A(afO, A1, 3);
    }
    { // ph8: cross-slot ahead-read (B0 + A0-q0) for next iteration
      __builtin_amdgcn_s_barrier();
      if (more) { stage_one(A, row0 + 0,   K, kC, A1, 0,  wv, lane); FENCE;
                  stage_one(A, row0 + 128, K, kC, A1, 64, wv, lane); }
      G192_MFMA(afO, bfrO, 3);
      if (more) { G192_RD_B(bfrE, B0); G192_RD_A(afE, A0, 0); }
    }
  }

  // ---- epilogue: per-wave 128 rows x 48 cols at (row0 + wr*128, col0 + wc*48)
  if (mode == 0) {
#pragma unroll
    for (int i = 0; i < 8; ++i)
#pragma unroll
      for (int r = 0; r < 4; ++r) {
        const int row = row0 + wr * 128 + i * 16 + quad * 4 + r;
        float* cr = C + (size_t)row * N + col0 + wc * 48;
#pragma unroll
        for (int j = 0; j < 3; ++j) cr[j * 16 + mm] = acc[i][j][r];
      }
  } else {
#pragma unroll
    for (int j = 0; j < 3; ++j) {
      const int gcolj = col0 + wc * 48 + j * 16;   // 16-aligned: one head per j-block
      const int which = gcolj >> 11;               // 0:q 1:k 2:v
      const int h = (gcolj >> 7) & 15;
      const int coff = (gcolj & 127) + mm;
      if (which == 2) {
        // V: write transposed -> Vt(B,H,Dh,L).  4 consecutive l per 8B store.
#pragma unroll
        for (int i = 0; i < 8; ++i) {
          const int row = row0 + wr * 128 + i * 16 + quad * 4;
          const int bb = row >> 11, l = row & 2047;
          usvec4 o;
#pragma unroll
          for (int r = 0; r < 4; ++r) o[r] = f2bf(acc[i][j][r]);
          *(usvec4*)(Vo + ((size_t)(bb * 16 + h) * 128 + coff) * 2048 + l) = o;
        }
      } else {
        ushort_t* dst = (which == 0) ? Qo : Ko;
#pragma unroll
        for (int i = 0; i < 8; ++i)
#pragma unroll
          for (int r = 0; r < 4; ++r) {
            const int row = row0 + wr * 128 + i * 16 + quad * 4 + r;
            const int bb = row >> 11, l = row & 2047;
            dst[((size_t)(bb * 16 + h) * 2048 + l) * 128 + coff] = f2bf(acc[i][j][r]);
          }
      }
    }
  }
}

// ================================================================ 128x256 4-phase GEMM
// (proj: 32x8 = 256 blocks = 1 exact round; proven round-4 kernel, unchanged)
__device__ __forceinline__ void stage_a128(const ushort_t* __restrict__ G, const int row0,
                                           const int K, const int tk, ushort_t* ldsA,
                                           const int wv, const int lane) {
  const int rr = lane >> 3;
  const int kk = ((lane & 7) ^ rr) * 8;
  const int r = wv * 8 + rr;
  glds16(G + (size_t)(row0 + r) * K + tk + kk,      ldsA + (wv * 8) * 64);
  glds16(G + (size_t)(row0 + 64 + r) * K + tk + kk, ldsA + (64 + wv * 8) * 64);
}
__device__ __forceinline__ void stage_b128(const ushort_t* __restrict__ G, const int col0,
                                           const int K, const int tk, ushort_t* ldsB,
                                           const int u, const int wv, const int lane) {
  const int rr = lane >> 3;
  const int kk = ((lane & 7) ^ rr) * 8;
  const int r = u * 64 + wv * 8 + rr;
  glds16(G + (size_t)(col0 + r) * K + tk + kk,       ldsB + (u * 64 + wv * 8) * 64);
  glds16(G + (size_t)(col0 + 128 + r) * K + tk + kk, ldsB + (128 + u * 64 + wv * 8) * 64);
}

__global__ __launch_bounds__(512, 2) void gemm128(
    const ushort_t* __restrict__ A, const ushort_t* __restrict__ Bt,
    const int M, const int N, const int K, const int mode,
    float* __restrict__ C,
    ushort_t* __restrict__ Qo, ushort_t* __restrict__ Ko, ushort_t* __restrict__ Vo) {
  __shared__ __align__(16) ushort_t l128[2][24576];   // per slot: A[0..8191], B[8192..24575]

  const int tid = threadIdx.x, wv = tid >> 6, lane = tid & 63;
  const int quad = lane >> 4, mm = lane & 15;
  const int wr = wv >> 2, wc = wv & 3;   // 2M x 4N

  const int nwg = gridDim.x, ntx = N >> 8;
  const int bid = blockIdx.x;
  const int swz = (bid & 7) * (nwg >> 3) + (bid >> 3);
  const int by = swz / ntx, bx = swz - by * ntx;
  const int row0 = by * 128, col0 = bx * 256;

  fvec4 acc[4][4];
#pragma unroll
  for (int m = 0; m < 4; ++m)
#pragma unroll
    for (int j = 0; j < 4; ++j) acc[m][j] = (fvec4){0.f, 0.f, 0.f, 0.f};

  ushort_t* A0 = &l128[0][0];     ushort_t* B0 = &l128[0][8192];
  ushort_t* A1 = &l128[1][0];     ushort_t* B1 = &l128[1][8192];

  short8 bfr[4][2];

  stage_b128(Bt, col0, K, 0,  B0, 0, wv, lane); FENCE;
  stage_b128(Bt, col0, K, 0,  B0, 1, wv, lane); FENCE;
  stage_a128(A,  row0, K, 0,  A0,    wv, lane); FENCE;
  stage_b128(Bt, col0, K, 64, B1, 0, wv, lane); FENCE;
  stage_b128(Bt, col0, K, 64, B1, 1, wv, lane); FENCE;
  asm volatile("s_waitcnt vmcnt(4)" ::: "memory");
  __builtin_amdgcn_s_barrier();

  const int nit = K >> 7;
  for (int i = 0; i < nit; ++i) {
    const bool more = (i + 1 < nit);
    const int kA = i * 128 + 64;
    const int kB = i * 128 + 128;
    const int kC = i * 128 + 192;
    { // ph1
      stage_a128(A, row0, K, kA, A1, wv, lane);
      short8 af[4];
#pragma unroll
      for (int m = 0; m < 4; ++m) af[m] = fragld128(A0, wr * 64 + m * 16 + mm, 0, quad);
#pragma unroll
      for (int j = 0; j < 4; ++j) {
        bfr[j][0] = fragld128(B0, wc * 64 + j * 16 + mm, 0, quad);
        bfr[j][1] = fragld128(B0, wc * 64 + j * 16 + mm, 1, quad);
      }
      __builtin_amdgcn_s_setprio(1);
#pragma unroll
      for (int m = 0; m < 4; ++m)
#pragma unroll
        for (int j = 0; j < 4; ++j)
          acc[m][j] = __builtin_amdgcn_mfma_f32_16x16x32_bf16(af[m], bfr[j][0], acc[m][j], 0, 0, 0);
      __builtin_amdgcn_s_setprio(0);
      asm volatile("s_waitcnt lgkmcnt(0)" ::: "memory");
      __builtin_amdgcn_sched_barrier(0);
    }
    { // ph2
      __builtin_amdgcn_s_barrier();
      if (more) { stage_b128(Bt, col0, K, kB, B0, 0, wv, lane); FENCE;
                  stage_b128(Bt, col0, K, kB, B0, 1, wv, lane); FENCE; }
      if (more) { asm volatile("s_waitcnt vmcnt(4)" ::: "memory"); }
      else      { asm volatile("s_waitcnt vmcnt(0)" ::: "memory"); }
      short8 af[4];
#pragma unroll
      for (int m = 0; m < 4; ++m) af[m] = fragld128(A0, wr * 64 + m * 16 + mm, 1, quad);
      __builtin_amdgcn_s_setprio(1);
#pragma unroll
      for (int m = 0; m < 4; ++m)
#pragma unroll
        for (int j = 0; j < 4; ++j)
          acc[m][j] = __builtin_amdgcn_mfma_f32_16x16x32_bf16(af[m], bfr[j][1], acc[m][j], 0, 0, 0);
      __builtin_amdgcn_s_setprio(0);
    }
    { // ph3
      __builtin_amdgcn_s_barrier();
      if (more) stage_a128(A, row0, K, kB, A0, wv, lane);
      short8 af[4];
#pragma unroll
      for (int m = 0; m < 4; ++m) af[m] = fragld128(A1, wr * 64 + m * 16 + mm, 0, quad);
#pragma unroll
      for (int j = 0; j < 4; ++j) {
        bfr[j][0] = fragld128(B1, wc * 64 + j * 16 + mm, 0, quad);
        bfr[j][1] = fragld128(B1, wc * 64 + j * 16 + mm, 1, quad);
      }
      __builtin_amdgcn_s_setprio(1);
#pragma unroll
      for (int m = 0; m < 4; ++m)
#pragma unroll
        for (int j = 0; j < 4; ++j)
          acc[m][j] = __builtin_amdgcn_mfma_f32_16x16x32_bf16(af[m], bfr[j][0], acc[m][j], 0, 0, 0);
      __builtin_amdgcn_s_setprio(0);
      asm volatile("s_waitcnt lgkmcnt(0)" ::: "memory");
      __builtin_amdgcn_sched_barrier(0);
    }
    { // ph4
      __builtin_amdgcn_s_barrier();
      if (more) { stage_b128(Bt, col0, K, kC, B1, 0, wv, lane); FENCE;
                  stage_b128(Bt, col0, K, kC, B1, 1, wv, lane); FENCE;
                  asm volatile("s_waitcnt vmcnt(4)" ::: "memory"); }
      short8 af[4];
#pragma unroll
      for (int m = 0; m < 4; ++m) af[m] = fragld128(A1, wr * 64 + m * 16 + mm, 1, quad);
      __builtin_amdgcn_s_setprio(1);
#pragma unroll
      for (int m = 0; m < 4; ++m)
#pragma unroll
        for (int j = 0; j < 4; ++j)
          acc[m][j] = __builtin_amdgcn_mfma_f32_16x16x32_bf16(af[m], bfr[j][1], acc[m][j], 0, 0, 0);
      __builtin_amdgcn_s_setprio(0);
      __builtin_amdgcn_s_barrier();
    }
  }

  if (mode == 0) {
#pragma unroll
    for (int m = 0; m < 4; ++m)
#pragma unroll
      for (int r = 0; r < 4; ++r) {
        const int row = row0 + wr * 64 + m * 16 + quad * 4 + r;
        float* cr = C + (size_t)row * N + col0 + wc * 64;
#pragma unroll
        for (int j = 0; j < 4; ++j) cr[j * 16 + mm] = acc[m][j][r];
      }
  } else {
    const int gcol = col0 + wc * 64;
    const int which = gcol >> 11;
    const int h = (gcol >> 7) & 15;
    const int coff = gcol & 127;
    ushort_t* dst = (which == 0) ? Qo : (which == 1) ? Ko : Vo;
#pragma unroll
    for (int m = 0; m < 4; ++m)
#pragma unroll
      for (int r = 0; r < 4; ++r) {
        const int row = row0 + wr * 64 + m * 16 + quad * 4 + r;
        const int bb = row >> 11, l = row & 2047;
        ushort_t* dr = dst + ((size_t)(bb * 16 + h) * 2048 + l) * 128 + coff;
#pragma unroll
        for (int j = 0; j < 4; ++j) dr[j * 16 + mm] = f2bf(acc[m][j][r]);
      }
  }
}

// ---------------------------------------------------------------- RoPE in-place on K only
// (Q rope is fused into flash_kernel's register Q-load — round 10.)
// Vectorized: one thread rotates 8 consecutive (d, d+64) pairs via short8.
__global__ __launch_bounds__(256) void ropek_kernel(ushort_t* Kb) {
  const int gid = blockIdx.x * 256 + threadIdx.x;   // 2048*256 = 524288
  const int pd0 = (gid & 7) * 8;
  const int row = gid >> 3;      // b*H*L + h*L + l   (0..65535)
  const int l = row & 2047;
  ushort_t* base = Kb + (size_t)row * 128;
  const short8 va = *(const short8*)(base + pd0);
  const short8 vb = *(const short8*)(base + pd0 + 64);
  short8 oa, ob;
  const float fl = (float)l;
#pragma unroll
  for (int i = 0; i < 8; ++i) {
    const int pd = pd0 + i;
    const float a  = bf2f((ushort_t)va[i]);
    const float bv = bf2f((ushort_t)vb[i]);
    const float invf_rev = exp2f(-(float)pd * 0.20762050593045702f) * 0.15915494309189535f;
    float rev = fl * invf_rev;
    rev -= floorf(rev);                         // [0,1)
    const float ang = rev * 6.283185307179586f;
    float s, c;
    __sincosf(ang, &s, &c);
    oa[i] = (short)f2bf(a * c - bv * s);
    ob[i] = (short)f2bf(bv * c + a * s);
  }
  *(short8*)(base + pd0)      = oa;
  *(short8*)(base + pd0 + 64) = ob;
}

// ---------------------------------------------------------------- flash attention v2
// Round-10: Q-rope (+softmax scale) fused into the register Q-load — pairs
// (d, d+64) map to (qf[c], qf[c+4]) lane-locally; same f32 math + RNE bf16
// rounding as the standalone rope kernel (numerics identical).  Vt now comes
// from gemm192p's direct transposed V write (vtrans kernel removed).
__global__ __launch_bounds__(256, 2) void flash_kernel(
    const ushort_t* __restrict__ Qb, const ushort_t* __restrict__ Kb,
    const ushort_t* __restrict__ Vt, const int* __restrict__ am,
    ushort_t* __restrict__ Y) {
  __shared__ __align__(16) ushort_t lK[2][8192];
  __shared__ __align__(16) ushort_t lV[2][8192];
  __shared__ float lds_l[128];

  const int tid = threadIdx.x, wv = tid >> 6, lane = tid & 63;
  const int lh = lane >> 5, cq = lane & 31;
  const int bid = blockIdx.x;
  const int bh = bid & 31;
  const int idx = (bid >> 5) & 7;
  const int qi = (bid >> 8) ? (15 - idx) : idx;    // balanced (c, c+256) pairing
  const int b = bh >> 4, head = bh & 15;
  const size_t qkBase = (size_t)bh * (2048 * 128);
  const int qb = qi * 128 + wv * 32;
  const int q = qb + cq;

  unsigned fullbits = 0;
  {
    const int* amr = am + b * 2048;
#pragma unroll
    for (int rgn = 0; rgn < 4; ++rgn) {
      const int4 a0 = *(const int4*)(amr + rgn * 512 + lane * 8);
      const int4 a1 = *(const int4*)(amr + rgn * 512 + lane * 8 + 4);
      const bool ok8 = a0.x && a0.y && a0.z && a0.w && a1.x && a1.y && a1.z && a1.w;
      const unsigned long long bal = __ballot(ok8);
#pragma unroll
      for (int tt = 0; tt < 8; ++tt)
        fullbits |= ((((bal >> (8 * tt)) & 0xFFull) == 0xFFull) ? 1u : 0u) << (rgn * 8 + tt);
    }
  }

  short8 qf[8];
  {
    const ushort_t* qrow = Qb + qkBase + (size_t)q * 128;
#pragma unroll
    for (int c = 0; c < 8; ++c) qf[c] = *(const short8*)(qrow + c * 16 + lh * 8);
    // fused RoPE + 1/sqrt(Dh) scale, lane-local: pd = c*16 + lh*8 + j in [0,64)
    const float fl = (float)q;
#pragma unroll
    for (int c = 0; c < 4; ++c)
#pragma unroll
      for (int j = 0; j < 8; ++j) {
        const int pd = c * 16 + lh * 8 + j;
        const float a  = bf2f((ushort_t)qf[c][j]);
        const float bv = bf2f((ushort_t)qf[c + 4][j]);
        const float invf_rev = exp2f(-(float)pd * 0.20762050593045702f) * 0.15915494309189535f;
        float rev = fl * invf_rev;
        rev -= floorf(rev);
        const float ang = rev * 6.283185307179586f;
        float s, cs;
        __sincosf(ang, &s, &cs);
        qf[c][j]     = (short)f2bf((a * cs - bv * s) * 0.08838834764831845f);
        qf[c + 4][j] = (short)f2bf((bv * cs + a * s) * 0.08838834764831845f);
      }
  }

  fvec16 yacc[4];
#pragma unroll
  for (int i = 0; i < 4; ++i)
#pragma unroll
    for (int r = 0; r < 16; ++r) yacc[i][r] = 0.f;
  float psum = 0.f;

#define FLASH_STAGE(dK, dV, kk0)                                                          \
  _Pragma("unroll")                                                                       \
  for (int it = 0; it < 4; ++it) {                                                        \
    const int f_ = it * 4 + wv;                                                           \
    const int ct_ = f_ >> 3, c_ = f_ & 7;                                                 \
    glds16(Kb + qkBase + (size_t)((kk0) + ct_ * 32 + cq) * 128 + c_ * 16 + lh * 8,        \
           (dK) + f_ * 512);                                                              \
    const int dt_ = f_ >> 2, kc_ = f_ & 3;                                                \
    glds16(Vt + ((size_t)bh * 128 + dt_ * 32 + cq) * 2048 + (kk0) + kc_ * 16 + lh * 8,    \
           (dV) + f_ * 512);                                                              \
  }

  const int nt = qi * 2 + 2;
  FLASH_STAGE(&lK[0][0], &lV[0][0], 0)
  __syncthreads();

  int cur = 0;
  for (int t = 0; t < nt; ++t) {
    const int k0 = t * 64;
    if (t + 1 < nt) {
      FLASH_STAGE(&lK[cur ^ 1][0], &lV[cur ^ 1][0], k0 + 64)
    }

    if (k0 <= qb + 31) {
      const ushort_t* bK = &lK[cur][0];
      const ushort_t* bV = &lV[cur][0];
      const bool maskfull = (fullbits >> t) & 1u;
      unsigned long long keymask = ~0ull;
      if (!maskfull) keymask = __ballot(am[b * 2048 + k0 + lane] != 0);
      const bool fullvalid = (k0 + 63 <= qb) && maskfull;

#pragma unroll
      for (int ct = 0; ct < 2; ++ct) {
        fvec16 sA_, sB_;
#pragma unroll
        for (int r = 0; r < 16; ++r) { sA_[r] = 0.f; sB_[r] = 0.f; }
        __builtin_amdgcn_s_setprio(1);
#pragma unroll
        for (int c = 0; c < 4; ++c) {
          short8 kf = *(const short8*)(bK + (ct * 8 + c) * 512 + lane * 8);
          sA_ = __builtin_amdgcn_mfma_f32_32x32x16_bf16(kf, qf[c], sA_, 0, 0, 0);
        }
#pragma unroll
        for (int c = 4; c < 8; ++c) {
          short8 kf = *(const short8*)(bK + (ct * 8 + c) * 512 + lane * 8);
          sB_ = __builtin_amdgcn_mfma_f32_32x32x16_bf16(kf, qf[c], sB_, 0, 0, 0);
        }
        __builtin_amdgcn_s_setprio(0);
        float p[16];
        if (fullvalid) {
#pragma unroll
          for (int r = 0; r < 16; ++r) p[r] = __expf(sA_[r] + sB_[r]);
        } else {
#pragma unroll
          for (int r = 0; r < 16; ++r) {
            const int kl = (r & 3) + 8 * (r >> 2) + 4 * lh + ct * 32;
            const bool ok = (k0 + kl <= q) && (((keymask >> kl) & 1ull) != 0);
            p[r] = ok ? __expf(sA_[r] + sB_[r]) : 0.f;
          }
        }
#pragma unroll
        for (int r = 0; r < 16; ++r) psum += p[r];
        unsigned pk[8];
#pragma unroll
        for (int j = 0; j < 8; ++j) {
          __hip_bfloat162 t2 = __float22bfloat162_rn(make_float2(p[2 * j], p[2 * j + 1]));
          pk[j] = *(unsigned*)&t2;
        }
#pragma unroll
        for (int kc2 = 0; kc2 < 2; ++kc2) {
          unsigned a0 = pk[kc2 * 4 + 0], a2 = pk[kc2 * 4 + 2];
          unsigned a1 = pk[kc2 * 4 + 1], a3 = pk[kc2 * 4 + 3];
          swap32(a0, a2);
          swap32(a1, a3);
          union { unsigned u[4]; short8 s; } pf;
          pf.u[0] = a0; pf.u[1] = a1; pf.u[2] = a2; pf.u[3] = a3;
          const int kc = ct * 2 + kc2;
          __builtin_amdgcn_s_setprio(1);
#pragma unroll
          for (int dt = 0; dt < 4; ++dt) {
            short8 vf = *(const short8*)(bV + (dt * 4 + kc) * 512 + lane * 8);
            yacc[dt] = __builtin_amdgcn_mfma_f32_32x32x16_bf16(pf.s, vf, yacc[dt], 0, 0, 0);
          }
          __builtin_amdgcn_s_setprio(0);
        }
      }
    }
    __syncthreads();
    cur ^= 1;
  }
#undef FLASH_STAGE

  psum += __shfl_xor(psum, 32);
  if (lane < 32) lds_l[wv * 32 + lane] = psum;
  float inv16[16];
#pragma unroll
  for (int r = 0; r < 16; ++r)
    inv16[r] = 1.f / lds_l[wv * 32 + (r & 3) + 8 * (r >> 2) + 4 * lh];

#pragma unroll
  for (int dt = 0; dt < 4; ++dt)
#pragma unroll
    for (int r = 0; r < 16; ++r) {
      const int qloc = (r & 3) + 8 * (r >> 2) + 4 * lh;
      ushort_t* dst = Y + ((size_t)(b * 2048 + qb + qloc)) * 2048 + head * 128 + dt * 32 + cq;
      *dst = f2bf(yacc[dt][r] * inv16[r]);
    }
}

// ---------------------------------------------------------------- launch
extern "C" void kernel_launch(void* const* d_in, const int* in_sizes, int n_in,
                              void* d_out, int out_size, void* d_ws, size_t ws_size,
                              hipStream_t stream) {
  const float* x      = (const float*)d_in[0];
  const int*   amask  = (const int*)d_in[1];
  const float* w_qkv  = (const float*)d_in[2];
  const float* w_proj = (const float*)d_in[3];

  ushort_t* xb     = (ushort_t*)d_ws;          // 8,388,608   (dead after gemm1)
  ushort_t* wqkvT  = xb + 8388608;             // 12,582,912  (dead after gemm1)
  ushort_t* wprojT = wqkvT + 12582912;         // 4,194,304
  ushort_t* Qb     = wprojT + 4194304;         // 8,388,608
  ushort_t* Kb     = Qb + 8388608;             // 8,388,608
  ushort_t* Vt     = Kb + 8388608;             // 8,388,608  (V written TRANSPOSED here)
  ushort_t* Yb     = xb;                       // reuse

  cast_f32_bf16<<<8192, 256, 0, stream>>>(x, xb);
  tcast2<<<dim3(128, 32), 256, 0, stream>>>(w_qkv, wqkvT, w_proj, wprojT);
  gemm192p<<<512, 512, 0, stream>>>(xb, wqkvT, 4096, 6144, 2048, 1,
                                    nullptr, Qb, Kb, Vt);
  ropek_kernel<<<2048, 256, 0, stream>>>(Kb);
  flash_kernel<<<512, 256, 0, stream>>>(Qb, Kb, Vt, amask, Yb);
  gemm128<<<256, 512, 0, stream>>>(Yb, wprojT, 4096, 2048, 2048, 0,
                                   (float*)d_out, nullptr, nullptr, nullptr);
}

// Round 12
// 359.039 us; speedup vs baseline: 1.0822x; 1.0026x over previous
//
#include <hip/hip_runtime.h>
#include <hip/hip_bf16.h>

// Problem constants: B=2, L=2048, D=2048, H=16, Dh=128, 3D=6144
typedef unsigned short ushort_t;
typedef __attribute__((ext_vector_type(4))) float fvec4;
typedef __attribute__((ext_vector_type(16))) float fvec16;
typedef __attribute__((ext_vector_type(8))) short short8;   // 8 bf16 (4 VGPRs) - MFMA A/B frag
typedef __attribute__((ext_vector_type(4))) unsigned short usvec4;
typedef __attribute__((ext_vector_type(2))) unsigned int uvec2;

typedef const __attribute__((address_space(1))) void* gas_ptr;
typedef __attribute__((address_space(3))) void* las_ptr;

__device__ __forceinline__ void glds16(const void* g, void* l) {
  // async global->LDS, 16B/lane, LDS dest = wave-uniform base + lane*16
  __builtin_amdgcn_global_load_lds((gas_ptr)g, (las_ptr)l, 16, 0, 0);
}

__device__ __forceinline__ ushort_t f2bf(float f) {
  unsigned u = __float_as_uint(f);
  u += 0x7FFFu + ((u >> 16) & 1u);   // RNE
  return (ushort_t)(u >> 16);
}
__device__ __forceinline__ float bf2f(ushort_t h) {
  return __uint_as_float(((unsigned)h) << 16);
}

// permlane32_swap: a' = [a.lo32lanes, b.lo32lanes], b' = [a.hi, b.hi]
__device__ __forceinline__ void swap32(unsigned& a, unsigned& b) {
#if __has_builtin(__builtin_amdgcn_permlane32_swap)
  uvec2 r = __builtin_amdgcn_permlane32_swap(a, b, false, false);
  a = r[0]; b = r[1];
#else
  const unsigned sa = (unsigned)__shfl_xor((int)a, 32);
  const unsigned sb = (unsigned)__shfl_xor((int)b, 32);
  const bool hi = (threadIdx.x & 32) != 0;
  const unsigned na = hi ? sb : a;
  const unsigned nb = hi ? b : sa;
  a = na; b = nb;
#endif
}

// ---------------------------------------------------------------- prep (round 11/12):
// ONE launch doing both x-cast (bid < 8192) and the two weight transposes
// (bid >= 8192; 4096 blocks = 128 bx x 32 by).  Bodies byte-identical to the
// round-10 cast_f32_bf16 / tcast2 kernels (both passing).
__global__ __launch_bounds__(256) void prep_kernel(const float* __restrict__ X,
                                                   ushort_t* __restrict__ Xb,
                                                   const float* __restrict__ Wq,
                                                   ushort_t* __restrict__ Wqt,
                                                   const float* __restrict__ Wp,
                                                   ushort_t* __restrict__ Wpt) {
  const int bid = blockIdx.x;
  const int t = threadIdx.x;
  if (bid < 8192) {                          // ---- cast x -> bf16
    const size_t i = ((size_t)bid * 256 + t) * 4;
    const fvec4 v = *(const fvec4*)(X + i);
    usvec4 o;
    o[0] = f2bf(v[0]); o[1] = f2bf(v[1]); o[2] = f2bf(v[2]); o[3] = f2bf(v[3]);
    *(usvec4*)(Xb + i) = o;
    return;
  }
  // ---- transpose+cast weights: W(Kd,Nd) -> Wt(Nd,Kd) bf16
  __shared__ float ls[64][65];
  const int t2 = bid - 8192;                 // 0..4095
  const int by = t2 >> 7;                    // 0..31
  int bx = t2 & 127;                         // 0..127
  const float* W; ushort_t* Wt; int Nd;
  if (bx < 96) { W = Wq; Wt = Wqt; Nd = 6144; }
  else         { bx -= 96; W = Wp; Wt = Wpt; Nd = 2048; }
  const int Kd = 2048;
  const int n0 = bx * 64, k0 = by * 64;
  const int kr = t >> 4, nc = (t & 15) * 4;
#pragma unroll
  for (int it = 0; it < 4; ++it) {
    const fvec4 v = *(const fvec4*)(W + (size_t)(k0 + it * 16 + kr) * Nd + n0 + nc);
    ls[it * 16 + kr][nc + 0] = v[0];
    ls[it * 16 + kr][nc + 1] = v[1];
    ls[it * 16 + kr][nc + 2] = v[2];
    ls[it * 16 + kr][nc + 3] = v[3];
  }
  __syncthreads();
  const int nr = t >> 2, kg = (t & 3) * 16;
  __align__(16) ushort_t tmp[16];
#pragma unroll
  for (int i = 0; i < 16; ++i) tmp[i] = f2bf(ls[kg + i][nr]);
  ushort_t* dst = Wt + (size_t)(n0 + nr) * Kd + k0 + kg;
  *(short8*)(dst)     = *(const short8*)(tmp);
  *(short8*)(dst + 8) = *(const short8*)(tmp + 8);
}

#define FENCE asm volatile("" ::: "memory")

// ---------------- shared GEMM helpers (T2 swizzle: pre-swizzled global k-chunk;
// reads XOR (row&7)<<4 into the 16B-slot bits; LDS row = 64 ushorts = 128 B)
__device__ __forceinline__ void stage_one(const ushort_t* __restrict__ G, const int grow,
                                          const int K, const int tk, ushort_t* ldsmat,
                                          const int lrow0, const int wv, const int lane) {
  const int rr = lane >> 3;                     // row within 8-row group (= row&7 of global)
  const int kk = ((lane & 7) ^ rr) * 8;         // pre-swizzled global k-chunk (ushorts)
  glds16(G + (size_t)(grow + wv * 8 + rr) * K + tk + kk,
         ldsmat + (lrow0 + wv * 8) * 64);
}

// A-frag read with {0,1,2,3}->{0,2,1,3} 64-row block permute (gemm192 A only)
__device__ __forceinline__ short8 frag_ld(const ushort_t* ldsmat, const int rbase,
                                          const int kc, const int quad, const int mm) {
  const int r = rbase + mm;                     // global row within tile
  const int blk = r >> 6;
  const int pblk = ((blk & 1) << 1) | (blk >> 1);   // {0,1,2,3}->{0,2,1,3}
  const int ldsrow = pblk * 64 + (r & 63);
  const int kb = (kc * 64 + quad * 16) ^ ((mm & 7) << 4);   // swizzled byte-in-row
  return *(const short8*)(ldsmat + ldsrow * 64 + (kb >> 1));
}

// identity-layout frag read (gemm128 A/B, gemm192 B)
__device__ __forceinline__ short8 fragld128(const ushort_t* mat, const int row,
                                            const int kc, const int quad) {
  const int kb = (kc * 64 + quad * 16) ^ ((row & 7) << 4);
  return *(const short8*)(mat + row * 64 + (kb >> 1));
}

// ================================================================ 256x192 8-phase GEMM
// REGISTER-PREFETCH version (benched r8-r10: ~103-107 µs QKV).  BM=256, BN=192,
// BK=64, 512 thr = 8 waves (2M x 4N), per-wave 128x48 (acc[8][3]).  LDS 112 KiB.
// Grid QKV = 16x32 = 512 blocks = 2 exact rounds at 1 block/CU.
// V output (which==2) written DIRECTLY TRANSPOSED to Vt (B,H,Dh,L).
#define G192_RD_A(dst_, Am, q_)                                               \
  dst_[0][0] = frag_ld(Am, wr * 128 + (q_) * 32,      0, quad, mm);           \
  dst_[0][1] = frag_ld(Am, wr * 128 + (q_) * 32,      1, quad, mm);           \
  dst_[1][0] = frag_ld(Am, wr * 128 + (q_) * 32 + 16, 0, quad, mm);           \
  dst_[1][1] = frag_ld(Am, wr * 128 + (q_) * 32 + 16, 1, quad, mm);

#define G192_RD_B(dst_, Bm)                                                   \
  _Pragma("unroll")                                                           \
  for (int j = 0; j < 3; ++j) {                                               \
    dst_[j][0] = fragld128(Bm, wc * 48 + j * 16 + mm, 0, quad);               \
    dst_[j][1] = fragld128(Bm, wc * 48 + j * 16 + mm, 1, quad);               \
  }

#define G192_MFMA(af_, bf_, q_)                                               \
  __builtin_amdgcn_s_setprio(1);                                              \
  _Pragma("unroll")                                                           \
  for (int ii = 0; ii < 2; ++ii)                                              \
  _Pragma("unroll")                                                           \
  for (int j = 0; j < 3; ++j) {                                               \
    acc[(q_) * 2 + ii][j] = __builtin_amdgcn_mfma_f32_16x16x32_bf16(          \
        af_[ii][0], bf_[j][0], acc[(q_) * 2 + ii][j], 0, 0, 0);               \
    acc[(q_) * 2 + ii][j] = __builtin_amdgcn_mfma_f32_16x16x32_bf16(          \
        af_[ii][1], bf_[j][1], acc[(q_) * 2 + ii][j], 0, 0, 0);               \
  }                                                                           \
  __builtin_amdgcn_s_setprio(0);                                              \
  __builtin_amdgcn_sched_barrier(0);

__global__ __launch_bounds__(512, 2) void gemm192p(
    const ushort_t* __restrict__ A, const ushort_t* __restrict__ Bt,
    const int M, const int N, const int K, const int mode,
    float* __restrict__ C,
    ushort_t* __restrict__ Qo, ushort_t* __restrict__ Ko, ushort_t* __restrict__ Vo) {
  __shared__ __align__(16) ushort_t lds[2][28672];   // per slot: A[0..16383], B[16384..28671]

  const int tid = threadIdx.x, wv = tid >> 6, lane = tid & 63;
  const int quad = lane >> 4, mm = lane & 15;
  const int wr = wv >> 2, wc = wv & 3;   // 2M x 4N

  const int nwg = gridDim.x, ntx = N / 192;
  const int bid = blockIdx.x;
  const int swz = (bid & 7) * (nwg >> 3) + (bid >> 3);
  const int by = swz / ntx, bx = swz - by * ntx;
  const int row0 = by * 256, col0 = bx * 192;

  fvec4 acc[8][3];
#pragma unroll
  for (int i = 0; i < 8; ++i)
#pragma unroll
    for (int j = 0; j < 3; ++j) acc[i][j] = (fvec4){0.f, 0.f, 0.f, 0.f};

  short8 bfrE[3][2], bfrO[3][2];
  short8 afE[2][2], afO[2][2];

  ushort_t* A0 = &lds[0][0];      ushort_t* B0 = &lds[0][16384];
  ushort_t* A1 = &lds[1][0];      ushort_t* B1 = &lds[1][16384];

  // ---- prologue: tile0 {b0,b1,b2,c0,c1,c2,c3} + tile1 {b0,b1,b2,c0,c2} = 12 glds
  stage_one(Bt, col0 + 0,   K, 0,  B0, 0,   wv, lane); FENCE;
  stage_one(Bt, col0 + 64,  K, 0,  B0, 64,  wv, lane); FENCE;
  stage_one(Bt, col0 + 128, K, 0,  B0, 128, wv, lane); FENCE;
  stage_one(A,  row0 + 0,   K, 0,  A0, 0,   wv, lane); FENCE;
  stage_one(A,  row0 + 64,  K, 0,  A0, 128, wv, lane); FENCE;   // c1 -> pblk 2
  stage_one(A,  row0 + 128, K, 0,  A0, 64,  wv, lane); FENCE;   // c2 -> pblk 1
  stage_one(A,  row0 + 192, K, 0,  A0, 192, wv, lane); FENCE;
  stage_one(Bt, col0 + 0,   K, 64, B1, 0,   wv, lane); FENCE;
  stage_one(Bt, col0 + 64,  K, 64, B1, 64,  wv, lane); FENCE;
  stage_one(Bt, col0 + 128, K, 64, B1, 128, wv, lane); FENCE;
  stage_one(A,  row0 + 0,   K, 64, A1, 0,   wv, lane); FENCE;
  stage_one(A,  row0 + 128, K, 64, A1, 64,  wv, lane); FENCE;
  asm volatile("s_waitcnt vmcnt(5)" ::: "memory");   // tile0 landed; tile1's 5 float
  __builtin_amdgcn_s_barrier();                      // all waves confirmed tile0
  // ph1's fragments, read ahead of the loop:
  G192_RD_B(bfrE, B0);
  G192_RD_A(afE, A0, 0);

  const int nit = K >> 7;                 // iterations of 2 K-tiles
  for (int i = 0; i < nit; ++i) {
    const bool more = (i + 1 < nit);
    const int kA = i * 128 + 64;          // tile 2i+1
    const int kB = i * 128 + 128;         // tile 2i+2
    const int kC = i * 128 + 192;         // tile 2i+3
    { // ph1
      __builtin_amdgcn_s_barrier();
      stage_one(A, row0 + 64,  K, kA, A1, 128, wv, lane); FENCE;
      stage_one(A, row0 + 192, K, kA, A1, 192, wv, lane);
      G192_MFMA(afE, bfrE, 0);
      G192_RD_A(afO, A0, 1);
    }
    { // ph2
      __builtin_amdgcn_s_barrier();
      if (more) { stage_one(Bt, col0 + 0,  K, kB, B0, 0,  wv, lane); FENCE;
                  stage_one(Bt, col0 + 64, K, kB, B0, 64, wv, lane); }
      G192_MFMA(afO, bfrE, 1);
      G192_RD_A(afE, A0, 2);
    }
    { // ph3: vmcnt(3) confirms tile 2i+1 (s1) before ph4's barrier
      __builtin_amdgcn_s_barrier();
      if (more) { stage_one(Bt, col0 + 128, K, kB, B0, 128, wv, lane);
                  asm volatile("s_waitcnt vmcnt(3)" ::: "memory");
      } else {    asm volatile("s_waitcnt vmcnt(0)" ::: "memory"); }
      G192_MFMA(afE, bfrE, 2);
      G192_RD_A(afO, A0, 3);
    }
    { // ph4: cross-slot ahead-read (B1 + A1-q0), safe after barrier
      __builtin_amdgcn_s_barrier();
      if (more) { stage_one(A, row0 + 0,   K, kB, A0, 0,  wv, lane); FENCE;
                  stage_one(A, row0 + 128, K, kB, A0, 64, wv, lane); }
      G192_MFMA(afO, bfrE, 3);
      G192_RD_B(bfrO, B1);
      G192_RD_A(afE, A1, 0);
    }
    { // ph5
      __builtin_amdgcn_s_barrier();
      if (more) { stage_one(A, row0 + 64,  K, kB, A0, 128, wv, lane); FENCE;
                  stage_one(A, row0 + 192, K, kB, A0, 192, wv, lane); }
      G192_MFMA(afE, bfrO, 0);
      G192_RD_A(afO, A1, 1);
    }
    { // ph6
      __builtin_amdgcn_s_barrier();
      if (more) { stage_one(Bt, col0 + 0,  K, kC, B1, 0,  wv, lane); FENCE;
                  stage_one(Bt, col0 + 64, K, kC, B1, 64, wv, lane); }
      G192_MFMA(afO, bfrO, 1);
      G192_RD_A(afE, A1, 2);
    }
    { // ph7: vmcnt(3) confirms tile 2i+2 (s0) before ph8's barrier
      __builtin_amdgcn_s_barrier();
      if (more) { stage_one(Bt, col0 + 128, K, kC, B1, 128, wv, lane);
                  asm volatile("s_waitcnt vmcnt(3)" ::: "memory"); }
      G192_MFMA(afE, bfrO, 2);
      G192_RD_A(afO, A1, 3);
    }
    { // ph8: cross-slot ahead-read (B0 + A0-q0) for next iteration
      __builtin_amdgcn_s_barrier();
      if (more) { stage_one(A, row0 + 0,   K, kC, A1, 0,  wv, lane); FENCE;
                  stage_one(A, row0 + 128, K, kC, A1, 64, wv, lane); }
      G192_MFMA(afO, bfrO, 3);
      if (more) { G192_RD_B(bfrE, B0); G192_RD_A(afE, A0, 0); }
    }
  }

  // ---- epilogue: per-wave 128 rows x 48 cols at (row0 + wr*128, col0 + wc*48)
  if (mode == 0) {
#pragma unroll
    for (int i = 0; i < 8; ++i)
#pragma unroll
      for (int r = 0; r < 4; ++r) {
        const int row = row0 + wr * 128 + i * 16 + quad * 4 + r;
        float* cr = C + (size_t)row * N + col0 + wc * 48;
#pragma unroll
        for (int j = 0; j < 3; ++j) cr[j * 16 + mm] = acc[i][j][r];
      }
  } else {
#pragma unroll
    for (int j = 0; j < 3; ++j) {
      const int gcolj = col0 + wc * 48 + j * 16;   // 16-aligned: one head per j-block
      const int which = gcolj >> 11;               // 0:q 1:k 2:v
      const int h = (gcolj >> 7) & 15;
      const int coff = (gcolj & 127) + mm;
      if (which == 2) {
        // V: write transposed -> Vt(B,H,Dh,L).  4 consecutive l per 8B store.
#pragma unroll
        for (int i = 0; i < 8; ++i) {
          const int row = row0 + wr * 128 + i * 16 + quad * 4;
          const int bb = row >> 11, l = row & 2047;
          usvec4 o;
#pragma unroll
          for (int r = 0; r < 4; ++r) o[r] = f2bf(acc[i][j][r]);
          *(usvec4*)(Vo + ((size_t)(bb * 16 + h) * 128 + coff) * 2048 + l) = o;
        }
      } else {
        ushort_t* dst = (which == 0) ? Qo : Ko;
#pragma unroll
        for (int i = 0; i < 8; ++i)
#pragma unroll
          for (int r = 0; r < 4; ++r) {
            const int row = row0 + wr * 128 + i * 16 + quad * 4 + r;
            const int bb = row >> 11, l = row & 2047;
            dst[((size_t)(bb * 16 + h) * 2048 + l) * 128 + coff] = f2bf(acc[i][j][r]);
          }
      }
    }
  }
}

// ================================================================ 128x256 4-phase GEMM
// (proj: 32x8 = 256 blocks = 1 exact round; proven round-4 kernel, unchanged)
__device__ __forceinline__ void stage_a128(const ushort_t* __restrict__ G, const int row0,
                                           const int K, const int tk, ushort_t* ldsA,
                                           const int wv, const int lane) {
  const int rr = lane >> 3;
  const int kk = ((lane & 7) ^ rr) * 8;
  const int r = wv * 8 + rr;
  glds16(G + (size_t)(row0 + r) * K + tk + kk,      ldsA + (wv * 8) * 64);
  glds16(G + (size_t)(row0 + 64 + r) * K + tk + kk, ldsA + (64 + wv * 8) * 64);
}
__device__ __forceinline__ void stage_b128(const ushort_t* __restrict__ G, const int col0,
                                           const int K, const int tk, ushort_t* ldsB,
                                           const int u, const int wv, const int lane) {
  const int rr = lane >> 3;
  const int kk = ((lane & 7) ^ rr) * 8;
  const int r = u * 64 + wv * 8 + rr;
  glds16(G + (size_t)(col0 + r) * K + tk + kk,       ldsB + (u * 64 + wv * 8) * 64);
  glds16(G + (size_t)(col0 + 128 + r) * K + tk + kk, ldsB + (128 + u * 64 + wv * 8) * 64);
}

__global__ __launch_bounds__(512, 2) void gemm128(
    const ushort_t* __restrict__ A, const ushort_t* __restrict__ Bt,
    const int M, const int N, const int K, const int mode,
    float* __restrict__ C,
    ushort_t* __restrict__ Qo, ushort_t* __restrict__ Ko, ushort_t* __restrict__ Vo) {
  __shared__ __align__(16) ushort_t l128[2][24576];   // per slot: A[0..8191], B[8192..24575]

  const int tid = threadIdx.x, wv = tid >> 6, lane = tid & 63;
  const int quad = lane >> 4, mm = lane & 15;
  const int wr = wv >> 2, wc = wv & 3;   // 2M x 4N

  const int nwg = gridDim.x, ntx = N >> 8;
  const int bid = blockIdx.x;
  const int swz = (bid & 7) * (nwg >> 3) + (bid >> 3);
  const int by = swz / ntx, bx = swz - by * ntx;
  const int row0 = by * 128, col0 = bx * 256;

  fvec4 acc[4][4];
#pragma unroll
  for (int m = 0; m < 4; ++m)
#pragma unroll
    for (int j = 0; j < 4; ++j) acc[m][j] = (fvec4){0.f, 0.f, 0.f, 0.f};

  ushort_t* A0 = &l128[0][0];     ushort_t* B0 = &l128[0][8192];
  ushort_t* A1 = &l128[1][0];     ushort_t* B1 = &l128[1][8192];

  short8 bfr[4][2];

  stage_b128(Bt, col0, K, 0,  B0, 0, wv, lane); FENCE;
  stage_b128(Bt, col0, K, 0,  B0, 1, wv, lane); FENCE;
  stage_a128(A,  row0, K, 0,  A0,    wv, lane); FENCE;
  stage_b128(Bt, col0, K, 64, B1, 0, wv, lane); FENCE;
  stage_b128(Bt, col0, K, 64, B1, 1, wv, lane); FENCE;
  asm volatile("s_waitcnt vmcnt(4)" ::: "memory");
  __builtin_amdgcn_s_barrier();

  const int nit = K >> 7;
  for (int i = 0; i < nit; ++i) {
    const bool more = (i + 1 < nit);
    const int kA = i * 128 + 64;
    const int kB = i * 128 + 128;
    const int kC = i * 128 + 192;
    { // ph1
      stage_a128(A, row0, K, kA, A1, wv, lane);
      short8 af[4];
#pragma unroll
      for (int m = 0; m < 4; ++m) af[m] = fragld128(A0, wr * 64 + m * 16 + mm, 0, quad);
#pragma unroll
      for (int j = 0; j < 4; ++j) {
        bfr[j][0] = fragld128(B0, wc * 64 + j * 16 + mm, 0, quad);
        bfr[j][1] = fragld128(B0, wc * 64 + j * 16 + mm, 1, quad);
      }
      __builtin_amdgcn_s_setprio(1);
#pragma unroll
      for (int m = 0; m < 4; ++m)
#pragma unroll
        for (int j = 0; j < 4; ++j)
          acc[m][j] = __builtin_amdgcn_mfma_f32_16x16x32_bf16(af[m], bfr[j][0], acc[m][j], 0, 0, 0);
      __builtin_amdgcn_s_setprio(0);
      asm volatile("s_waitcnt lgkmcnt(0)" ::: "memory");
      __builtin_amdgcn_sched_barrier(0);
    }
    { // ph2
      __builtin_amdgcn_s_barrier();
      if (more) { stage_b128(Bt, col0, K, kB, B0, 0, wv, lane); FENCE;
                  stage_b128(Bt, col0, K, kB, B0, 1, wv, lane); FENCE; }
      if (more) { asm volatile("s_waitcnt vmcnt(4)" ::: "memory"); }
      else      { asm volatile("s_waitcnt vmcnt(0)" ::: "memory"); }
      short8 af[4];
#pragma unroll
      for (int m = 0; m < 4; ++m) af[m] = fragld128(A0, wr * 64 + m * 16 + mm, 1, quad);
      __builtin_amdgcn_s_setprio(1);
#pragma unroll
      for (int m = 0; m < 4; ++m)
#pragma unroll
        for (int j = 0; j < 4; ++j)
          acc[m][j] = __builtin_amdgcn_mfma_f32_16x16x32_bf16(af[m], bfr[j][1], acc[m][j], 0, 0, 0);
      __builtin_amdgcn_s_setprio(0);
    }
    { // ph3
      __builtin_amdgcn_s_barrier();
      if (more) stage_a128(A, row0, K, kB, A0, wv, lane);
      short8 af[4];
#pragma unroll
      for (int m = 0; m < 4; ++m) af[m] = fragld128(A1, wr * 64 + m * 16 + mm, 0, quad);
#pragma unroll
      for (int j = 0; j < 4; ++j) {
        bfr[j][0] = fragld128(B1, wc * 64 + j * 16 + mm, 0, quad);
        bfr[j][1] = fragld128(B1, wc * 64 + j * 16 + mm, 1, quad);
      }
      __builtin_amdgcn_s_setprio(1);
#pragma unroll
      for (int m = 0; m < 4; ++m)
#pragma unroll
        for (int j = 0; j < 4; ++j)
          acc[m][j] = __builtin_amdgcn_mfma_f32_16x16x32_bf16(af[m], bfr[j][0], acc[m][j], 0, 0, 0);
      __builtin_amdgcn_s_setprio(0);
      asm volatile("s_waitcnt lgkmcnt(0)" ::: "memory");
      __builtin_amdgcn_sched_barrier(0);
    }
    { // ph4
      __builtin_amdgcn_s_barrier();
      if (more) { stage_b128(Bt, col0, K, kC, B1, 0, wv, lane); FENCE;
                  stage_b128(Bt, col0, K, kC, B1, 1, wv, lane); FENCE;
                  asm volatile("s_waitcnt vmcnt(4)" ::: "memory"); }
      short8 af[4];
#pragma unroll
      for (int m = 0; m < 4; ++m) af[m] = fragld128(A1, wr * 64 + m * 16 + mm, 1, quad);
      __builtin_amdgcn_s_setprio(1);
#pragma unroll
      for (int m = 0; m < 4; ++m)
#pragma unroll
        for (int j = 0; j < 4; ++j)
          acc[m][j] = __builtin_amdgcn_mfma_f32_16x16x32_bf16(af[m], bfr[j][1], acc[m][j], 0, 0, 0);
      __builtin_amdgcn_s_setprio(0);
      __builtin_amdgcn_s_barrier();
    }
  }

  if (mode == 0) {
#pragma unroll
    for (int m = 0; m < 4; ++m)
#pragma unroll
      for (int r = 0; r < 4; ++r) {
        const int row = row0 + wr * 64 + m * 16 + quad * 4 + r;
        float* cr = C + (size_t)row * N + col0 + wc * 64;
#pragma unroll
        for (int j = 0; j < 4; ++j) cr[j * 16 + mm] = acc[m][j][r];
      }
  } else {
    const int gcol = col0 + wc * 64;
    const int which = gcol >> 11;
    const int h = (gcol >> 7) & 15;
    const int coff = gcol & 127;
    ushort_t* dst = (which == 0) ? Qo : (which == 1) ? Ko : Vo;
#pragma unroll
    for (int m = 0; m < 4; ++m)
#pragma unroll
      for (int r = 0; r < 4; ++r) {
        const int row = row0 + wr * 64 + m * 16 + quad * 4 + r;
        const int bb = row >> 11, l = row & 2047;
        ushort_t* dr = dst + ((size_t)(bb * 16 + h) * 2048 + l) * 128 + coff;
#pragma unroll
        for (int j = 0; j < 4; ++j) dr[j * 16 + mm] = f2bf(acc[m][j][r]);
      }
  }
}

// ---------------------------------------------------------------- RoPE in-place on K only
// (Q rope is fused into flash_kernel's register Q-load.)
// Vectorized: one thread rotates 8 consecutive (d, d+64) pairs via short8.
__global__ __launch_bounds__(256) void ropek_kernel(ushort_t* Kb) {
  const int gid = blockIdx.x * 256 + threadIdx.x;   // 2048*256 = 524288
  const int pd0 = (gid & 7) * 8;
  const int row = gid >> 3;      // b*H*L + h*L + l   (0..65535)
  const int l = row & 2047;
  ushort_t* base = Kb + (size_t)row * 128;
  const short8 va = *(const short8*)(base + pd0);
  const short8 vb = *(const short8*)(base + pd0 + 64);
  short8 oa, ob;
  const float fl = (float)l;
#pragma unroll
  for (int i = 0; i < 8; ++i) {
    const int pd = pd0 + i;
    const float a  = bf2f((ushort_t)va[i]);
    const float bv = bf2f((ushort_t)vb[i]);
    const float invf_rev = exp2f(-(float)pd * 0.20762050593045702f) * 0.15915494309189535f;
    float rev = fl * invf_rev;
    rev -= floorf(rev);                         // [0,1)
    const float ang = rev * 6.283185307179586f;
    float s, c;
    __sincosf(ang, &s, &c);
    oa[i] = (short)f2bf(a * c - bv * s);
    ob[i] = (short)f2bf(bv * c + a * s);
  }
  *(short8*)(base + pd0)      = oa;
  *(short8*)(base + pd0 + 64) = ob;
}

// ---------------------------------------------------------------- flash attention v2
// (round-10 passing version, unchanged: Q-rope + scale fused into Q-load;
// balanced (c, c+256) qi pairing; mask-fullness precompute; split QK chains)
__global__ __launch_bounds__(256, 2) void flash_kernel(
    const ushort_t* __restrict__ Qb, const ushort_t* __restrict__ Kb,
    const ushort_t* __restrict__ Vt, const int* __restrict__ am,
    ushort_t* __restrict__ Y) {
  __shared__ __align__(16) ushort_t lK[2][8192];
  __shared__ __align__(16) ushort_t lV[2][8192];
  __shared__ float lds_l[128];

  const int tid = threadIdx.x, wv = tid >> 6, lane = tid & 63;
  const int lh = lane >> 5, cq = lane & 31;
  const int bid = blockIdx.x;
  const int bh = bid & 31;
  const int idx = (bid >> 5) & 7;
  const int qi = (bid >> 8) ? (15 - idx) : idx;    // balanced (c, c+256) pairing
  const int b = bh >> 4, head = bh & 15;
  const size_t qkBase = (size_t)bh * (2048 * 128);
  const int qb = qi * 128 + wv * 32;
  const int q = qb + cq;

  unsigned fullbits = 0;
  {
    const int* amr = am + b * 2048;
#pragma unroll
    for (int rgn = 0; rgn < 4; ++rgn) {
      const int4 a0 = *(const int4*)(amr + rgn * 512 + lane * 8);
      const int4 a1 = *(const int4*)(amr + rgn * 512 + lane * 8 + 4);
      const bool ok8 = a0.x && a0.y && a0.z && a0.w && a1.x && a1.y && a1.z && a1.w;
      const unsigned long long bal = __ballot(ok8);
#pragma unroll
      for (int tt = 0; tt < 8; ++tt)
        fullbits |= ((((bal >> (8 * tt)) & 0xFFull) == 0xFFull) ? 1u : 0u) << (rgn * 8 + tt);
    }
  }

  short8 qf[8];
  {
    const ushort_t* qrow = Qb + qkBase + (size_t)q * 128;
#pragma unroll
    for (int c = 0; c < 8; ++c) qf[c] = *(const short8*)(qrow + c * 16 + lh * 8);
    // fused RoPE + 1/sqrt(Dh) scale, lane-local: pd = c*16 + lh*8 + j in [0,64)
    const float fl = (float)q;
#pragma unroll
    for (int c = 0; c < 4; ++c)
#pragma unroll
      for (int j = 0; j < 8; ++j) {
        const int pd = c * 16 + lh * 8 + j;
        const float a  = bf2f((ushort_t)qf[c][j]);
        const float bv = bf2f((ushort_t)qf[c + 4][j]);
        const float invf_rev = exp2f(-(float)pd * 0.20762050593045702f) * 0.15915494309189535f;
        float rev = fl * invf_rev;
        rev -= floorf(rev);
        const float ang = rev * 6.283185307179586f;
        float s, cs;
        __sincosf(ang, &s, &cs);
        qf[c][j]     = (short)f2bf((a * cs - bv * s) * 0.08838834764831845f);
        qf[c + 4][j] = (short)f2bf((bv * cs + a * s) * 0.08838834764831845f);
      }
  }

  fvec16 yacc[4];
#pragma unroll
  for (int i = 0; i < 4; ++i)
#pragma unroll
    for (int r = 0; r < 16; ++r) yacc[i][r] = 0.f;
  float psum = 0.f;

#define FLASH_STAGE(dK, dV, kk0)                                                          \
  _Pragma("unroll")                                                                       \
  for (int it = 0; it < 4; ++it) {                                                        \
    const int f_ = it * 4 + wv;                                                           \
    const int ct_ = f_ >> 3, c_ = f_ & 7;                                                 \
    glds16(Kb + qkBase + (size_t)((kk0) + ct_ * 32 + cq) * 128 + c_ * 16 + lh * 8,        \
           (dK) + f_ * 512);                                                              \
    const int dt_ = f_ >> 2, kc_ = f_ & 3;                                                \
    glds16(Vt + ((size_t)bh * 128 + dt_ * 32 + cq) * 2048 + (kk0) + kc_ * 16 + lh * 8,    \
           (dV) + f_ * 512);                                                              \
  }

  const int nt = qi * 2 + 2;
  FLASH_STAGE(&lK[0][0], &lV[0][0], 0)
  __syncthreads();

  int cur = 0;
  for (int t = 0; t < nt; ++t) {
    const int k0 = t * 64;
    if (t + 1 < nt) {
      FLASH_STAGE(&lK[cur ^ 1][0], &lV[cur ^ 1][0], k0 + 64)
    }

    if (k0 <= qb + 31) {
      const ushort_t* bK = &lK[cur][0];
      const ushort_t* bV = &lV[cur][0];
      const bool maskfull = (fullbits >> t) & 1u;
      unsigned long long keymask = ~0ull;
      if (!maskfull) keymask = __ballot(am[b * 2048 + k0 + lane] != 0);
      const bool fullvalid = (k0 + 63 <= qb) && maskfull;

#pragma unroll
      for (int ct = 0; ct < 2; ++ct) {
        fvec16 sA_, sB_;
#pragma unroll
        for (int r = 0; r < 16; ++r) { sA_[r] = 0.f; sB_[r] = 0.f; }
        __builtin_amdgcn_s_setprio(1);
#pragma unroll
        for (int c = 0; c < 4; ++c) {
          short8 kf = *(const short8*)(bK + (ct * 8 + c) * 512 + lane * 8);
          sA_ = __builtin_amdgcn_mfma_f32_32x32x16_bf16(kf, qf[c], sA_, 0, 0, 0);
        }
#pragma unroll
        for (int c = 4; c < 8; ++c) {
          short8 kf = *(const short8*)(bK + (ct * 8 + c) * 512 + lane * 8);
          sB_ = __builtin_amdgcn_mfma_f32_32x32x16_bf16(kf, qf[c], sB_, 0, 0, 0);
        }
        __builtin_amdgcn_s_setprio(0);
        float p[16];
        if (fullvalid) {
#pragma unroll
          for (int r = 0; r < 16; ++r) p[r] = __expf(sA_[r] + sB_[r]);
        } else {
#pragma unroll
          for (int r = 0; r < 16; ++r) {
            const int kl = (r & 3) + 8 * (r >> 2) + 4 * lh + ct * 32;
            const bool ok = (k0 + kl <= q) && (((keymask >> kl) & 1ull) != 0);
            p[r] = ok ? __expf(sA_[r] + sB_[r]) : 0.f;
          }
        }
#pragma unroll
        for (int r = 0; r < 16; ++r) psum += p[r];
        unsigned pk[8];
#pragma unroll
        for (int j = 0; j < 8; ++j) {
          __hip_bfloat162 t2 = __float22bfloat162_rn(make_float2(p[2 * j], p[2 * j + 1]));
          pk[j] = *(unsigned*)&t2;
        }
#pragma unroll
        for (int kc2 = 0; kc2 < 2; ++kc2) {
          unsigned a0 = pk[kc2 * 4 + 0], a2 = pk[kc2 * 4 + 2];
          unsigned a1 = pk[kc2 * 4 + 1], a3 = pk[kc2 * 4 + 3];
          swap32(a0, a2);
          swap32(a1, a3);
          union { unsigned u[4]; short8 s; } pf;
          pf.u[0] = a0; pf.u[1] = a1; pf.u[2] = a2; pf.u[3] = a3;
          const int kc = ct * 2 + kc2;
          __builtin_amdgcn_s_setprio(1);
#pragma unroll
          for (int dt = 0; dt < 4; ++dt) {
            short8 vf = *(const short8*)(bV + (dt * 4 + kc) * 512 + lane * 8);
            yacc[dt] = __builtin_amdgcn_mfma_f32_32x32x16_bf16(pf.s, vf, yacc[dt], 0, 0, 0);
          }
          __builtin_amdgcn_s_setprio(0);
        }
      }
    }
    __syncthreads();
    cur ^= 1;
  }
#undef FLASH_STAGE

  psum += __shfl_xor(psum, 32);
  if (lane < 32) lds_l[wv * 32 + lane] = psum;
  float inv16[16];
#pragma unroll
  for (int r = 0; r < 16; ++r)
    inv16[r] = 1.f / lds_l[wv * 32 + (r & 3) + 8 * (r >> 2) + 4 * lh];

#pragma unroll
  for (int dt = 0; dt < 4; ++dt)
#pragma unroll
    for (int r = 0; r < 16; ++r) {
      const int qloc = (r & 3) + 8 * (r >> 2) + 4 * lh;
      ushort_t* dst = Y + ((size_t)(b * 2048 + qb + qloc)) * 2048 + head * 128 + dt * 32 + cq;
      *dst = f2bf(yacc[dt][r] * inv16[r]);
    }
}

// ---------------------------------------------------------------- launch (5 kernels)
extern "C" void kernel_launch(void* const* d_in, const int* in_sizes, int n_in,
                              void* d_out, int out_size, void* d_ws, size_t ws_size,
                              hipStream_t stream) {
  const float* x      = (const float*)d_in[0];
  const int*   amask  = (const int*)d_in[1];
  const float* w_qkv  = (const float*)d_in[2];
  const float* w_proj = (const float*)d_in[3];

  ushort_t* xb     = (ushort_t*)d_ws;          // 8,388,608   (dead after gemm1)
  ushort_t* wqkvT  = xb + 8388608;             // 12,582,912  (dead after gemm1)
  ushort_t* wprojT = wqkvT + 12582912;         // 4,194,304
  ushort_t* Qb     = wprojT + 4194304;         // 8,388,608
  ushort_t* Kb     = Qb + 8388608;             // 8,388,608
  ushort_t* Vt     = Kb + 8388608;             // 8,388,608  (V written TRANSPOSED here)
  ushort_t* Yb     = xb;                       // reuse

  prep_kernel<<<12288, 256, 0, stream>>>(x, xb, w_qkv, wqkvT, w_proj, wprojT);
  gemm192p<<<512, 512, 0, stream>>>(xb, wqkvT, 4096, 6144, 2048, 1,
                                    nullptr, Qb, Kb, Vt);
  ropek_kernel<<<2048, 256, 0, stream>>>(Kb);
  flash_kernel<<<512, 256, 0, stream>>>(Qb, Kb, Vt, amask, Yb);
  gemm128<<<256, 512, 0, stream>>>(Yb, wprojT, 4096, 2048, 2048, 0,
                                   (float*)d_out, nullptr, nullptr, nullptr);
}